// Round 3
// baseline (4166.017 us; speedup 1.0000x reference)
//
#include <hip/hip_runtime.h>
#include <hip/hip_fp16.h>

#define NN 50000
#define NE 150000
#define HD 512
#define HIDN 64
#define BN_EPS 1e-5f
#define SLOPE 0.01f

__device__ __forceinline__ float leaky(float v){ return v > 0.f ? v : SLOPE*v; }
__device__ __forceinline__ float h2fu(unsigned short u){ return __half2float(__ushort_as_half(u)); }
__device__ __forceinline__ unsigned short f2hu(float f){ return __half_as_ushort(__float2half(f)); }
__device__ __forceinline__ unsigned packh2(float a, float b){
  return (unsigned)f2hu(a) | ((unsigned)f2hu(b) << 16);
}

// ---------------- setup ----------------
__global__ void k_counts(const int* __restrict__ batch, int* __restrict__ counts){
  int i = blockIdx.x*blockDim.x + threadIdx.x;
  if (i < NN) atomicAdd(&counts[batch[i]], 1);
}
__global__ void k_invs_mask0(const int* __restrict__ batch, const int* __restrict__ counts,
                             const float* __restrict__ x, float* __restrict__ invs, int* __restrict__ m0){
  int i = blockIdx.x*blockDim.x + threadIdx.x;
  if (i < NN){
    invs[i] = rsqrtf((float)counts[batch[i]]);
    m0[i] = (fabsf(x[i]) > 0.f) ? 1 : 0;
  }
}
__global__ void k_mask_copy(const int* __restrict__ a, int* __restrict__ b){
  int i = blockIdx.x*blockDim.x + threadIdx.x;
  if (i < NN) b[i] = a[i];
}
__global__ void k_mask_prop(const int* __restrict__ mi, int* __restrict__ mo,
                            const int* __restrict__ src, const int* __restrict__ dst){
  int e = blockIdx.x*blockDim.x + threadIdx.x;
  if (e < NE){ if (mi[src[e]]) atomicOr(&mo[dst[e]], 1); }
}

// ---------------- CSR build (by dst) ----------------
__global__ void k_deg(const int* __restrict__ dst, int* __restrict__ deg){
  int e = blockIdx.x*blockDim.x + threadIdx.x;
  if (e < NE) atomicAdd(&deg[dst[e]], 1);
}
#define SCAN_CHUNK 49  // 1024*49 = 50176 >= NN
__global__ void k_scan(const int* __restrict__ deg, int* __restrict__ off, int* __restrict__ cur){
  __shared__ int part[1024];
  int t = threadIdx.x;
  int base = t * SCAN_CHUNK;
  int s = 0;
  for (int j = 0; j < SCAN_CHUNK; j++){ int i = base + j; if (i < NN) s += deg[i]; }
  part[t] = s;
  __syncthreads();
  for (int d = 1; d < 1024; d <<= 1){
    int add = (t >= d) ? part[t - d] : 0;
    __syncthreads();
    part[t] += add;
    __syncthreads();
  }
  int run = part[t] - s;   // exclusive prefix for this chunk
  for (int j = 0; j < SCAN_CHUNK; j++){
    int i = base + j;
    if (i < NN){ off[i] = run; cur[i] = run; run += deg[i]; }
  }
}
__global__ void k_scatter(const int* __restrict__ src, const int* __restrict__ dst,
                          int* __restrict__ cur, int* __restrict__ srcs){
  int e = blockIdx.x*blockDim.x + threadIdx.x;
  if (e < NE){
    int pos = atomicAdd(&cur[dst[e]], 1);
    srcs[pos] = src[e];
  }
}

// ---------------- conv1 front ----------------
__global__ void k_sagg_csr(const float* __restrict__ x, const int* __restrict__ off,
                           const int* __restrict__ deg, const int* __restrict__ srcs,
                           const float* __restrict__ epsp, float* __restrict__ h0){
  int i = blockIdx.x*blockDim.x + threadIdx.x;
  if (i < NN){
    float s = (1.f + epsp[0]) * x[i];
    int o = off[i], d = deg[i];
    for (int j = 0; j < d; j++) s += x[srcs[o + j]];
    h0[i] = s;
  }
}
// H1[i][c] = relu(h0[i]*w1[c] + b1[c]) -> fp16
__global__ void k_conv1_h1(const float* __restrict__ h0, const float* __restrict__ w1,
                           const float* __restrict__ b1, unsigned short* __restrict__ C){
  long idx = (long)blockIdx.x*blockDim.x + threadIdx.x;
  if (idx >= (long)NN*HD) return;
  int i = (int)(idx >> 9), c = (int)(idx & (HD-1));
  float v = fmaf(h0[i], w1[c], b1[c]);
  C[idx] = f2hu(v > 0.f ? v : 0.f);
}

// ---------------- gather+combine: G[i] = (1+eps)*X[i] + sum X[src], X fp32 -> G fp16 ----------------
__global__ void k_agg_csr(const float* __restrict__ X, const int* __restrict__ off,
                          const int* __restrict__ deg, const int* __restrict__ srcs,
                          const float* __restrict__ epsp, unsigned short* __restrict__ G){
  int i = blockIdx.x;
  int t = threadIdx.x;          // 128 threads, 4 channels each
  int c = t << 2;
  float4 acc = *(const float4*)(X + (size_t)i*HD + c);
  float ep = 1.f + epsp[0];
  acc.x *= ep; acc.y *= ep; acc.z *= ep; acc.w *= ep;
  int o = off[i], d = deg[i];
  for (int j = 0; j < d; j++){
    int s = srcs[o + j];
    float4 q = *(const float4*)(X + (size_t)s*HD + c);
    acc.x += q.x; acc.y += q.y; acc.z += q.z; acc.w += q.w;
  }
  uint2 r; r.x = packh2(acc.x, acc.y); r.y = packh2(acc.z, acc.w);
  *(uint2*)(G + (size_t)i*HD + c) = r;
}

// ---------------- GEMM: C[MxNC](fp16) = act(A[Mx512] @ W[512xNC] + b) * mask ----------------
// A input: fp16 (INF32=false) or fp32 (INF32=true). W/bias fp32.
template<int ACT, bool MASK, bool INF32>
__global__ __launch_bounds__(256) void k_gemm(const void* __restrict__ Ain,
    const float* __restrict__ W, const float* __restrict__ bias, const int* __restrict__ mask,
    unsigned short* __restrict__ C, int M, int NC)
{
  __shared__ float As[16][68];
  __shared__ float Ws[16][64];
  const int tid = threadIdx.x;
  const int m0 = blockIdx.x * 64;
  const int n0 = blockIdx.y * 64;
  const int lw_k = tid >> 4;          // 0..15
  const int lw_n = (tid & 15) << 2;   // 0..60
  const int ty = tid >> 4, tx = tid & 15;
  float acc[4][4];
  #pragma unroll
  for (int i=0;i<4;i++){
    #pragma unroll
    for (int j=0;j<4;j++) acc[i][j]=0.f;
  }
  const float* Wp = W + (size_t)lw_k * NC + n0 + lw_n;

  if (INF32){
    const int lrow = tid >> 2;        // 0..63
    const int lk4  = (tid & 3) << 2;  // 0,4,8,12
    const int arow = m0 + lrow;
    const bool aload = arow < M;
    const float* Ap = (const float*)Ain + (size_t)arow * HD + lk4;
    for (int kt = 0; kt < HD; kt += 16){
      float4 av = make_float4(0.f,0.f,0.f,0.f);
      if (aload) av = *(const float4*)(Ap + kt);
      float4 wv = *(const float4*)(Wp + (size_t)kt * NC);
      __syncthreads();
      As[lk4+0][lrow]=av.x; As[lk4+1][lrow]=av.y;
      As[lk4+2][lrow]=av.z; As[lk4+3][lrow]=av.w;
      *(float4*)&Ws[lw_k][lw_n] = wv;
      __syncthreads();
      #pragma unroll
      for (int kk=0;kk<16;kk++){
        float a[4], w[4];
        *(float4*)a = *(const float4*)&As[kk][ty<<2];
        *(float4*)w = *(const float4*)&Ws[kk][tx<<2];
        #pragma unroll
        for (int i=0;i<4;i++){
          #pragma unroll
          for (int j=0;j<4;j++) acc[i][j] = fmaf(a[i], w[j], acc[i][j]);
        }
      }
    }
  } else {
    const int lrow = tid >> 1;          // 0..63 for tid<128
    const int lk8  = (tid & 1) << 3;    // 0 or 8
    const int arow = m0 + lrow;
    const bool aload = (tid < 128) && (arow < M);
    const unsigned short* Ap = (const unsigned short*)Ain + (size_t)arow * HD + lk8;
    for (int kt = 0; kt < HD; kt += 16){
      uint4 av = make_uint4(0,0,0,0);
      if (aload) av = *(const uint4*)(Ap + kt);
      float4 wv = *(const float4*)(Wp + (size_t)kt * NC);
      __syncthreads();
      if (tid < 128){
        As[lk8+0][lrow]=h2fu(av.x&0xFFFF); As[lk8+1][lrow]=h2fu(av.x>>16);
        As[lk8+2][lrow]=h2fu(av.y&0xFFFF); As[lk8+3][lrow]=h2fu(av.y>>16);
        As[lk8+4][lrow]=h2fu(av.z&0xFFFF); As[lk8+5][lrow]=h2fu(av.z>>16);
        As[lk8+6][lrow]=h2fu(av.w&0xFFFF); As[lk8+7][lrow]=h2fu(av.w>>16);
      }
      *(float4*)&Ws[lw_k][lw_n] = wv;
      __syncthreads();
      #pragma unroll
      for (int kk=0;kk<16;kk++){
        float a[4], w[4];
        *(float4*)a = *(const float4*)&As[kk][ty<<2];
        *(float4*)w = *(const float4*)&Ws[kk][tx<<2];
        #pragma unroll
        for (int i=0;i<4;i++){
          #pragma unroll
          for (int j=0;j<4;j++) acc[i][j] = fmaf(a[i], w[j], acc[i][j]);
        }
      }
    }
  }
  #pragma unroll
  for (int i=0;i<4;i++){
    int r = m0 + (ty<<2) + i;
    if (r >= M) continue;
    float mk = 1.f;
    if (MASK) mk = mask[r] ? 1.f : 0.f;
    int c0 = n0 + (tx<<2);
    float v[4];
    #pragma unroll
    for (int j=0;j<4;j++){
      float t = acc[i][j] + bias[c0+j];
      if (ACT==1) t = t>0.f?t:0.f;
      else if (ACT==2) t = leaky(t);
      v[j] = t * mk;
    }
    uint2 pk; pk.x = packh2(v[0],v[1]); pk.y = packh2(v[2],v[3]);
    *(uint2*)(C + (size_t)r*NC + c0) = pk;
  }
}

// ---------------- BN (fp16 data, fp32 stats) ----------------
// st[0..511]=sum, st[512..1023]=sumsq; thread owns channel pair c=2*tid
__global__ void k_bn_stats(const unsigned* __restrict__ Xu, float* __restrict__ st){
  int tid = threadIdx.x;
  float s0=0,s1=0,q0=0,q1=0;
  for (int r = blockIdx.x; r < NN; r += gridDim.x){
    unsigned u = Xu[(size_t)r*256 + tid];
    float v0=h2fu(u&0xFFFF), v1=h2fu(u>>16);
    s0+=v0; s1+=v1; q0+=v0*v0; q1+=v1*v1;
  }
  int c = tid<<1;
  unsafeAtomicAdd(&st[c],s0);      unsafeAtomicAdd(&st[c+1],s1);
  unsafeAtomicAdd(&st[HD+c],q0);   unsafeAtomicAdd(&st[HD+c+1],q1);
}
// T = (resid(fp32) + leaky(bn(Hin fp16)))*mask*invs -> T fp16 ; stats of T -> st2
template<bool RESID>
__global__ void k_bn_apply_stats(const unsigned* __restrict__ Hu, const float* __restrict__ g,
    const float* __restrict__ bb, const float* __restrict__ st,
    const float* __restrict__ Rf, const int* __restrict__ mask, const float* __restrict__ invs,
    unsigned* __restrict__ Tu, float* __restrict__ st2)
{
  int tid = threadIdx.x; int c = tid<<1;
  const float inv_n = 1.f/(float)NN;
  float mu0 = st[c]*inv_n, mu1 = st[c+1]*inv_n;
  float var0 = st[HD+c]*inv_n - mu0*mu0;
  float var1 = st[HD+c+1]*inv_n - mu1*mu1;
  float sc0 = g[c]*rsqrtf(var0+BN_EPS), sc1 = g[c+1]*rsqrtf(var1+BN_EPS);
  float sh0 = bb[c] - mu0*sc0, sh1 = bb[c+1] - mu1*sc1;
  float s0=0,s1=0,q0=0,q1=0;
  for (int r = blockIdx.x; r < NN; r += gridDim.x){
    unsigned u = Hu[(size_t)r*256 + tid];
    float v0 = leaky(fmaf(h2fu(u&0xFFFF), sc0, sh0));
    float v1 = leaky(fmaf(h2fu(u>>16),   sc1, sh1));
    if (RESID){
      float2 rr = *(const float2*)(Rf + (size_t)r*HD + c);
      v0 += rr.x; v1 += rr.y;
    }
    float w = mask[r] ? invs[r] : 0.f;
    v0 *= w; v1 *= w;
    Tu[(size_t)r*256 + tid] = packh2(v0, v1);
    s0+=v0; s1+=v1; q0+=v0*v0; q1+=v1*v1;
  }
  unsafeAtomicAdd(&st2[c],s0);      unsafeAtomicAdd(&st2[c+1],s1);
  unsafeAtomicAdd(&st2[HD+c],q0);   unsafeAtomicAdd(&st2[HD+c+1],q1);
}
// X(fp32) = bn(T fp16) with stats st
__global__ void k_bn_final(const unsigned* __restrict__ Tu, const float* __restrict__ g,
    const float* __restrict__ bb, const float* __restrict__ st, float* __restrict__ X)
{
  long i = (long)blockIdx.x*blockDim.x + threadIdx.x;   // over NN*256 uint pairs
  if (i >= (long)NN*256) return;
  int c = ((int)(i & 255)) << 1;
  const float inv_n = 1.f/(float)NN;
  float mu0 = st[c]*inv_n, mu1 = st[c+1]*inv_n;
  float var0 = st[HD+c]*inv_n - mu0*mu0;
  float var1 = st[HD+c+1]*inv_n - mu1*mu1;
  float sc0 = g[c]*rsqrtf(var0+BN_EPS), sc1 = g[c+1]*rsqrtf(var1+BN_EPS);
  float sh0 = bb[c] - mu0*sc0, sh1 = bb[c+1] - mu1*sc1;
  unsigned u = Tu[i];
  float2 o;
  o.x = fmaf(h2fu(u&0xFFFF), sc0, sh0);
  o.y = fmaf(h2fu(u>>16),   sc1, sh1);
  *(float2*)(X + (i<<1)) = o;
}

// ---------------- head ----------------
__global__ void k_lin2(const unsigned short* __restrict__ Z1, const float* __restrict__ w2,
    const float* __restrict__ b2, const int* __restrict__ mask, float* __restrict__ z2)
{
  int i = blockIdx.x*4 + (threadIdx.x >> 6);
  int lane = threadIdx.x & 63;
  if (i >= NN) return;
  float v = h2fu(Z1[(size_t)i*HIDN + lane]) * w2[lane];
  #pragma unroll
  for (int off=32; off>=1; off>>=1) v += __shfl_xor(v, off);
  if (lane == 0){
    float t = leaky(v + b2[0]);
    z2[i] = mask[i] ? t : 0.f;
  }
}
__device__ __forceinline__ unsigned fkey(float f){
  unsigned u = __float_as_uint(f);
  return (u & 0x80000000u) ? ~u : (u | 0x80000000u);
}
__device__ __forceinline__ float funkey(unsigned k){
  unsigned u = (k & 0x80000000u) ? (k & 0x7fffffffu) : ~k;
  return __uint_as_float(u);
}
__global__ void k_minmax(const float* __restrict__ z2, const int* __restrict__ batch,
                         unsigned* __restrict__ mx, unsigned* __restrict__ mn){
  int i = blockIdx.x*blockDim.x + threadIdx.x;
  if (i < NN){
    unsigned k = fkey(z2[i]); int g = batch[i];
    atomicMax(&mx[g], k); atomicMin(&mn[g], k);
  }
}
__global__ void k_final(const float* __restrict__ z2, const int* __restrict__ batch,
                        const unsigned* __restrict__ mx, const unsigned* __restrict__ mn,
                        float* __restrict__ out){
  int i = blockIdx.x*blockDim.x + threadIdx.x;
  if (i < NN){
    int g = batch[i];
    float bmax = funkey(mx[g]), bmin = funkey(mn[g]);
    out[i] = (z2[i] - bmin) / ((bmax + 1e-6f) - bmin);
  }
}

extern "C" void kernel_launch(void* const* d_in, const int* in_sizes, int n_in,
                              void* d_out, int out_size, void* d_ws, size_t ws_size,
                              hipStream_t stream)
{
  const float* x      = (const float*)d_in[0];
  const int*   ei     = (const int*)d_in[1];
  const int*   src    = ei;
  const int*   dst    = ei + NE;
  const int*   batch  = (const int*)d_in[2];
  const float* c1_w1  = (const float*)d_in[3];
  const float* c1_b1  = (const float*)d_in[4];
  const float* c1_w2  = (const float*)d_in[5];
  const float* c1_b2  = (const float*)d_in[6];
  const float* c1_bng = (const float*)d_in[7];
  const float* c1_bnb = (const float*)d_in[8];
  const float* eps1   = (const float*)d_in[9];
  const float* bn1_g  = (const float*)d_in[10];
  const float* bn1_b  = (const float*)d_in[11];
  const float* cw1    = (const float*)d_in[12];
  const float* cb1    = (const float*)d_in[13];
  const float* cw2    = (const float*)d_in[14];
  const float* cb2    = (const float*)d_in[15];
  const float* cbn_g  = (const float*)d_in[16];
  const float* cbn_b  = (const float*)d_in[17];
  const float* ceps   = (const float*)d_in[18];
  const float* bns_g  = (const float*)d_in[19];
  const float* bns_b  = (const float*)d_in[20];
  const float* l1_w   = (const float*)d_in[21];
  const float* l1_b   = (const float*)d_in[22];
  const float* l2_w   = (const float*)d_in[23];
  const float* l2_b   = (const float*)d_in[24];
  float* out = (float*)d_out;

  const size_t NH = (size_t)NN*HD;
  float* X = (float*)d_ws;                        // fp32 NH (residual stream)
  unsigned short* A = (unsigned short*)(X + NH);  // fp16 NH
  unsigned short* B = A + NH;                     // fp16 NH
  float* h0   = (float*)(B + NH);                 // NN
  float* invs = h0 + NN;                          // NN
  float* z2   = invs + NN;                        // NN
  float* st1  = z2 + NN;                          // 1024
  float* st2  = st1 + 1024;                       // 1024
  int* counts = (int*)(st2 + 1024);               // 64
  unsigned* mx = (unsigned*)(counts + 64);        // 64
  unsigned* mn = mx + 64;                         // 64
  int* deg  = (int*)(mn + 64);                    // NN
  int* off  = deg + NN;                           // NN
  int* cur  = off + NN;                           // NN
  int* srcs = cur + NN;                           // NE
  int* m[5];
  m[0] = srcs + NE;
  for (int k=1;k<5;k++) m[k] = m[k-1] + NN;

  unsigned* Au = (unsigned*)A;
  unsigned* Bu = (unsigned*)B;

  const int TPB = 256;
  dim3 gN((NN+TPB-1)/TPB);
  dim3 gE((NE+TPB-1)/TPB);
  dim3 gNH((unsigned)((NH + TPB-1)/TPB));
  dim3 gNH2((unsigned)((NH/2 + TPB-1)/TPB));
  dim3 ggemm((NN+63)/64, HD/64);

  // setup
  hipMemsetAsync(counts, 0, 64*sizeof(int), stream);
  k_counts<<<gN, TPB, 0, stream>>>(batch, counts);
  k_invs_mask0<<<gN, TPB, 0, stream>>>(batch, counts, x, invs, m[0]);
  for (int k=1;k<5;k++){
    k_mask_copy<<<gN,TPB,0,stream>>>(m[k-1], m[k]);
    k_mask_prop<<<gE,TPB,0,stream>>>(m[k-1], m[k], src, dst);
  }
  // CSR by dst
  hipMemsetAsync(deg, 0, NN*sizeof(int), stream);
  k_deg<<<gE,TPB,0,stream>>>(dst, deg);
  k_scan<<<1,1024,0,stream>>>(deg, off, cur);
  k_scatter<<<gE,TPB,0,stream>>>(src, dst, cur, srcs);

  // conv1: H1->A, gemm->B, bn_conv+leaky+scale->A(T), bn1->X
  k_sagg_csr<<<gN,TPB,0,stream>>>(x, off, deg, srcs, eps1, h0);
  k_conv1_h1<<<gNH,TPB,0,stream>>>(h0, c1_w1, c1_b1, A);
  k_gemm<1,false,false><<<ggemm,256,0,stream>>>(A, c1_w2, c1_b2, nullptr, B, NN, HD);
  hipMemsetAsync(st1, 0, 1024*sizeof(float), stream);
  k_bn_stats<<<512,256,0,stream>>>(Bu, st1);
  hipMemsetAsync(st2, 0, 1024*sizeof(float), stream);
  k_bn_apply_stats<false><<<512,256,0,stream>>>(Bu, c1_bng, c1_bnb, st1, nullptr, m[1], invs, Au, st2);
  k_bn_final<<<gNH2,TPB,0,stream>>>(Au, bn1_g, bn1_b, st2, X);

  // mid layers: agg X->A, g1 A->B, g2 B->A, stats A, apply (A,resid X)->B, final B->X
  for (int i=0;i<3;i++){
    k_agg_csr<<<NN,128,0,stream>>>(X, off, deg, srcs, ceps+i, A);
    k_gemm<1,false,false><<<ggemm,256,0,stream>>>(A, cw1 + (size_t)i*HD*HD, cb1 + (size_t)i*HD, nullptr, B, NN, HD);
    k_gemm<1,false,false><<<ggemm,256,0,stream>>>(B, cw2 + (size_t)i*HD*HD, cb2 + (size_t)i*HD, nullptr, A, NN, HD);
    hipMemsetAsync(st1, 0, 1024*sizeof(float), stream);
    k_bn_stats<<<512,256,0,stream>>>(Au, st1);
    hipMemsetAsync(st2, 0, 1024*sizeof(float), stream);
    k_bn_apply_stats<true><<<512,256,0,stream>>>(Au, cbn_g + (size_t)i*HD, cbn_b + (size_t)i*HD, st1, X, m[i+2], invs, Bu, st2);
    k_bn_final<<<gNH2,TPB,0,stream>>>(Bu, bns_g + (size_t)i*HD, bns_b + (size_t)i*HD, st2, X);
  }

  // head: lin1 (fp32 input X, leaky+mask) -> A, lin2 -> z2, min/max, normalize
  dim3 glin1((NN+63)/64, 1);
  k_gemm<2,true,true><<<glin1,256,0,stream>>>(X, l1_w, l1_b, m[4], A, NN, HIDN);
  k_lin2<<<(NN+3)/4,256,0,stream>>>(A, l2_w, l2_b, m[4], z2);
  hipMemsetAsync(mx, 0x00, 64*sizeof(unsigned), stream);
  hipMemsetAsync(mn, 0xFF, 64*sizeof(unsigned), stream);
  k_minmax<<<gN,TPB,0,stream>>>(z2, batch, mx, mn);
  k_final<<<gN,TPB,0,stream>>>(z2, batch, mx, mn, out);
}

// Round 4
// 2078.305 us; speedup vs baseline: 2.0045x; 2.0045x over previous
//
#include <hip/hip_runtime.h>
#include <hip/hip_fp16.h>

#define NN 50000
#define NE 150000
#define HD 512
#define HIDN 64
#define BN_EPS 1e-5f
#define SLOPE 0.01f

typedef _Float16 half8 __attribute__((ext_vector_type(8)));
typedef float floatx4 __attribute__((ext_vector_type(4)));

__device__ __forceinline__ float leaky(float v){ return v > 0.f ? v : SLOPE*v; }
__device__ __forceinline__ float h2fu(unsigned short u){ return __half2float(__ushort_as_half(u)); }
__device__ __forceinline__ unsigned short f2hu(float f){ return __half_as_ushort(__float2half(f)); }
__device__ __forceinline__ unsigned packh2(float a, float b){
  return (unsigned)f2hu(a) | ((unsigned)f2hu(b) << 16);
}

// ---------------- setup ----------------
__global__ void k_counts(const int* __restrict__ batch, int* __restrict__ counts){
  int i = blockIdx.x*blockDim.x + threadIdx.x;
  if (i < NN) atomicAdd(&counts[batch[i]], 1);
}
__global__ void k_invs_mask0(const int* __restrict__ batch, const int* __restrict__ counts,
                             const float* __restrict__ x, float* __restrict__ invs, int* __restrict__ m0){
  int i = blockIdx.x*blockDim.x + threadIdx.x;
  if (i < NN){
    invs[i] = rsqrtf((float)counts[batch[i]]);
    m0[i] = (fabsf(x[i]) > 0.f) ? 1 : 0;
  }
}
__global__ void k_mask_copy(const int* __restrict__ a, int* __restrict__ b){
  int i = blockIdx.x*blockDim.x + threadIdx.x;
  if (i < NN) b[i] = a[i];
}
__global__ void k_mask_prop(const int* __restrict__ mi, int* __restrict__ mo,
                            const int* __restrict__ src, const int* __restrict__ dst){
  int e = blockIdx.x*blockDim.x + threadIdx.x;
  if (e < NE){ if (mi[src[e]]) atomicOr(&mo[dst[e]], 1); }
}

// ---------------- CSR build (by dst) ----------------
__global__ void k_deg(const int* __restrict__ dst, int* __restrict__ deg){
  int e = blockIdx.x*blockDim.x + threadIdx.x;
  if (e < NE) atomicAdd(&deg[dst[e]], 1);
}
#define SCAN_CHUNK 49  // 1024*49 = 50176 >= NN
__global__ void k_scan(const int* __restrict__ deg, int* __restrict__ off, int* __restrict__ cur){
  __shared__ int part[1024];
  int t = threadIdx.x;
  int base = t * SCAN_CHUNK;
  int s = 0;
  for (int j = 0; j < SCAN_CHUNK; j++){ int i = base + j; if (i < NN) s += deg[i]; }
  part[t] = s;
  __syncthreads();
  for (int d = 1; d < 1024; d <<= 1){
    int add = (t >= d) ? part[t - d] : 0;
    __syncthreads();
    part[t] += add;
    __syncthreads();
  }
  int run = part[t] - s;   // exclusive prefix for this chunk
  for (int j = 0; j < SCAN_CHUNK; j++){
    int i = base + j;
    if (i < NN){ off[i] = run; cur[i] = run; run += deg[i]; }
  }
}
__global__ void k_scatter(const int* __restrict__ src, const int* __restrict__ dst,
                          int* __restrict__ cur, int* __restrict__ srcs){
  int e = blockIdx.x*blockDim.x + threadIdx.x;
  if (e < NE){
    int pos = atomicAdd(&cur[dst[e]], 1);
    srcs[pos] = src[e];
  }
}

// ---------------- weight prep: Wt[n][k] fp16 = W[k][n] fp32 ----------------
__global__ void k_w2ht(const float* __restrict__ W, unsigned short* __restrict__ Wt, int K, int N){
  __shared__ float t[32][33];
  int kb = blockIdx.x*32, nb = blockIdx.y*32;
  int tx = threadIdx.x & 31, ty = threadIdx.x >> 5;   // 32 x 8
  for (int r = 0; r < 32; r += 8)
    t[ty+r][tx] = W[(size_t)(kb+ty+r)*N + nb+tx];
  __syncthreads();
  for (int r = 0; r < 32; r += 8)
    Wt[(size_t)(nb+ty+r)*K + kb+tx] = f2hu(t[tx][ty+r]);
}

// ---------------- conv1 front ----------------
__global__ void k_sagg_csr(const float* __restrict__ x, const int* __restrict__ off,
                           const int* __restrict__ deg, const int* __restrict__ srcs,
                           const float* __restrict__ epsp, float* __restrict__ h0){
  int i = blockIdx.x*blockDim.x + threadIdx.x;
  if (i < NN){
    float s = (1.f + epsp[0]) * x[i];
    int o = off[i], d = deg[i];
    for (int j = 0; j < d; j++) s += x[srcs[o + j]];
    h0[i] = s;
  }
}
// H1[i][c] = relu(h0[i]*w1[c] + b1[c]) -> fp16
__global__ void k_conv1_h1(const float* __restrict__ h0, const float* __restrict__ w1,
                           const float* __restrict__ b1, unsigned short* __restrict__ C){
  long idx = (long)blockIdx.x*blockDim.x + threadIdx.x;
  if (idx >= (long)NN*HD) return;
  int i = (int)(idx >> 9), c = (int)(idx & (HD-1));
  float v = fmaf(h0[i], w1[c], b1[c]);
  C[idx] = f2hu(v > 0.f ? v : 0.f);
}

// ---------------- gather+combine: G[i] = (1+eps)*X[i] + sum X[src], X fp32 -> G fp16 ----------------
__global__ void k_agg_csr(const float* __restrict__ X, const int* __restrict__ off,
                          const int* __restrict__ deg, const int* __restrict__ srcs,
                          const float* __restrict__ epsp, unsigned short* __restrict__ G){
  int i = blockIdx.x;
  int t = threadIdx.x;          // 128 threads, 4 channels each
  int c = t << 2;
  float4 acc = *(const float4*)(X + (size_t)i*HD + c);
  float ep = 1.f + epsp[0];
  acc.x *= ep; acc.y *= ep; acc.z *= ep; acc.w *= ep;
  int o = off[i], d = deg[i];
  for (int j = 0; j < d; j++){
    int s = srcs[o + j];
    float4 q = *(const float4*)(X + (size_t)s*HD + c);
    acc.x += q.x; acc.y += q.y; acc.z += q.z; acc.w += q.w;
  }
  uint2 r; r.x = packh2(acc.x, acc.y); r.y = packh2(acc.z, acc.w);
  *(uint2*)(G + (size_t)i*HD + c) = r;
}

// ---------------- MFMA GEMM: C[Mx512](fp16) = relu(A[Mx512] @ W + b) ----------------
// A row-major fp16, Wt[n][k] fp16 (pre-transposed), bias fp32.
// 128x128 tile, 4 waves of 64x64 (4x4 MFMA 16x16x32), BK=64, single-buffer LDS.
__global__ __launch_bounds__(256) void k_gemm_mfma(const _Float16* __restrict__ A,
    const _Float16* __restrict__ Wt, const float* __restrict__ bias,
    _Float16* __restrict__ C, int M)
{
  constexpr int PK = 72;                     // padded row (halves): 144 B, 16B-aligned
  __shared__ _Float16 As[128*PK];
  __shared__ _Float16 Bs[128*PK];
  const int tid = threadIdx.x;
  const int m0 = blockIdx.x * 128;
  const int n0 = blockIdx.y * 128;
  const int w = tid >> 6, lane = tid & 63;
  const int wm = (w >> 1) << 6, wn = (w & 1) << 6;
  const int quad = lane >> 4, l16 = lane & 15;

  floatx4 acc[4][4] = {};

  // staging: 2 threads per row, 64 B (32 halves) each
  const int srow = tid >> 1;                 // 0..127
  const int skoff = (tid & 1) << 5;          // 0 or 32 halves
  const int arow = m0 + srow;
  const bool aok = arow < M;
  const _Float16* Ag = A  + (size_t)arow*HD + skoff;
  const _Float16* Bg = Wt + (size_t)(n0 + srow)*HD + skoff;
  _Float16* Asw = As + srow*PK + skoff;
  _Float16* Bsw = Bs + srow*PK + skoff;

  for (int kt = 0; kt < HD; kt += 64){
    half8 a0={},a1={},a2={},a3={};
    if (aok){
      a0 = *(const half8*)(Ag + kt);      a1 = *(const half8*)(Ag + kt + 8);
      a2 = *(const half8*)(Ag + kt + 16); a3 = *(const half8*)(Ag + kt + 24);
    }
    half8 b0 = *(const half8*)(Bg + kt);      half8 b1 = *(const half8*)(Bg + kt + 8);
    half8 b2 = *(const half8*)(Bg + kt + 16); half8 b3 = *(const half8*)(Bg + kt + 24);
    __syncthreads();
    *(half8*)(Asw)      = a0; *(half8*)(Asw + 8)  = a1;
    *(half8*)(Asw + 16) = a2; *(half8*)(Asw + 24) = a3;
    *(half8*)(Bsw)      = b0; *(half8*)(Bsw + 8)  = b1;
    *(half8*)(Bsw + 16) = b2; *(half8*)(Bsw + 24) = b3;
    __syncthreads();
    #pragma unroll
    for (int k0 = 0; k0 < 64; k0 += 32){
      half8 af[4], bf[4];
      #pragma unroll
      for (int t4 = 0; t4 < 4; t4++){
        af[t4] = *(const half8*)(As + (wm + t4*16 + l16)*PK + k0 + quad*8);
        bf[t4] = *(const half8*)(Bs + (wn + t4*16 + l16)*PK + k0 + quad*8);
      }
      #pragma unroll
      for (int mi = 0; mi < 4; mi++){
        #pragma unroll
        for (int ni = 0; ni < 4; ni++){
          acc[mi][ni] = __builtin_amdgcn_mfma_f32_16x16x32_f16(af[mi], bf[ni], acc[mi][ni], 0, 0, 0);
        }
      }
    }
  }
  // epilogue: D row = quad*4+reg, col = l16  (verified m89/m91 layout)
  #pragma unroll
  for (int mi = 0; mi < 4; mi++){
    #pragma unroll
    for (int reg = 0; reg < 4; reg++){
      int r = m0 + wm + mi*16 + quad*4 + reg;
      if (r < M){
        #pragma unroll
        for (int ni = 0; ni < 4; ni++){
          int c = n0 + wn + ni*16 + l16;
          float v = acc[mi][ni][reg] + bias[c];
          v = v > 0.f ? v : 0.f;
          C[(size_t)r*HD + c] = (_Float16)v;
        }
      }
    }
  }
}

// ---------------- vector GEMM (head lin1 only): C[MxNC](fp16) = act(A_f32[Mx512]@W+b)*mask ----------------
template<int ACT, bool MASK>
__global__ __launch_bounds__(256) void k_gemm_v(const float* __restrict__ Ain,
    const float* __restrict__ W, const float* __restrict__ bias, const int* __restrict__ mask,
    unsigned short* __restrict__ C, int M, int NC)
{
  __shared__ float As[16][68];
  __shared__ float Ws[16][64];
  const int tid = threadIdx.x;
  const int m0 = blockIdx.x * 64;
  const int n0 = blockIdx.y * 64;
  const int lw_k = tid >> 4;
  const int lw_n = (tid & 15) << 2;
  const int ty = tid >> 4, tx = tid & 15;
  float acc[4][4];
  #pragma unroll
  for (int i=0;i<4;i++){
    #pragma unroll
    for (int j=0;j<4;j++) acc[i][j]=0.f;
  }
  const float* Wp = W + (size_t)lw_k * NC + n0 + lw_n;
  const int lrow = tid >> 2;
  const int lk4  = (tid & 3) << 2;
  const int arow = m0 + lrow;
  const bool aload = arow < M;
  const float* Ap = Ain + (size_t)arow * HD + lk4;
  for (int kt = 0; kt < HD; kt += 16){
    float4 av = make_float4(0.f,0.f,0.f,0.f);
    if (aload) av = *(const float4*)(Ap + kt);
    float4 wv = *(const float4*)(Wp + (size_t)kt * NC);
    __syncthreads();
    As[lk4+0][lrow]=av.x; As[lk4+1][lrow]=av.y;
    As[lk4+2][lrow]=av.z; As[lk4+3][lrow]=av.w;
    *(float4*)&Ws[lw_k][lw_n] = wv;
    __syncthreads();
    #pragma unroll
    for (int kk=0;kk<16;kk++){
      float a[4], ww[4];
      *(float4*)a  = *(const float4*)&As[kk][ty<<2];
      *(float4*)ww = *(const float4*)&Ws[kk][tx<<2];
      #pragma unroll
      for (int i=0;i<4;i++){
        #pragma unroll
        for (int j=0;j<4;j++) acc[i][j] = fmaf(a[i], ww[j], acc[i][j]);
      }
    }
  }
  #pragma unroll
  for (int i=0;i<4;i++){
    int r = m0 + (ty<<2) + i;
    if (r >= M) continue;
    float mk = 1.f;
    if (MASK) mk = mask[r] ? 1.f : 0.f;
    int c0 = n0 + (tx<<2);
    float v[4];
    #pragma unroll
    for (int j=0;j<4;j++){
      float t = acc[i][j] + bias[c0+j];
      if (ACT==1) t = t>0.f?t:0.f;
      else if (ACT==2) t = leaky(t);
      v[j] = t * mk;
    }
    uint2 pk; pk.x = packh2(v[0],v[1]); pk.y = packh2(v[2],v[3]);
    *(uint2*)(C + (size_t)r*NC + c0) = pk;
  }
}

// ---------------- BN (fp16 data, fp32 stats) ----------------
__global__ void k_bn_stats(const unsigned* __restrict__ Xu, float* __restrict__ st){
  int tid = threadIdx.x;
  float s0=0,s1=0,q0=0,q1=0;
  for (int r = blockIdx.x; r < NN; r += gridDim.x){
    unsigned u = Xu[(size_t)r*256 + tid];
    float v0=h2fu(u&0xFFFF), v1=h2fu(u>>16);
    s0+=v0; s1+=v1; q0+=v0*v0; q1+=v1*v1;
  }
  int c = tid<<1;
  unsafeAtomicAdd(&st[c],s0);      unsafeAtomicAdd(&st[c+1],s1);
  unsafeAtomicAdd(&st[HD+c],q0);   unsafeAtomicAdd(&st[HD+c+1],q1);
}
template<bool RESID>
__global__ void k_bn_apply_stats(const unsigned* __restrict__ Hu, const float* __restrict__ g,
    const float* __restrict__ bb, const float* __restrict__ st,
    const float* __restrict__ Rf, const int* __restrict__ mask, const float* __restrict__ invs,
    unsigned* __restrict__ Tu, float* __restrict__ st2)
{
  int tid = threadIdx.x; int c = tid<<1;
  const float inv_n = 1.f/(float)NN;
  float mu0 = st[c]*inv_n, mu1 = st[c+1]*inv_n;
  float var0 = st[HD+c]*inv_n - mu0*mu0;
  float var1 = st[HD+c+1]*inv_n - mu1*mu1;
  float sc0 = g[c]*rsqrtf(var0+BN_EPS), sc1 = g[c+1]*rsqrtf(var1+BN_EPS);
  float sh0 = bb[c] - mu0*sc0, sh1 = bb[c+1] - mu1*sc1;
  float s0=0,s1=0,q0=0,q1=0;
  for (int r = blockIdx.x; r < NN; r += gridDim.x){
    unsigned u = Hu[(size_t)r*256 + tid];
    float v0 = leaky(fmaf(h2fu(u&0xFFFF), sc0, sh0));
    float v1 = leaky(fmaf(h2fu(u>>16),   sc1, sh1));
    if (RESID){
      float2 rr = *(const float2*)(Rf + (size_t)r*HD + c);
      v0 += rr.x; v1 += rr.y;
    }
    float ww = mask[r] ? invs[r] : 0.f;
    v0 *= ww; v1 *= ww;
    Tu[(size_t)r*256 + tid] = packh2(v0, v1);
    s0+=v0; s1+=v1; q0+=v0*v0; q1+=v1*v1;
  }
  unsafeAtomicAdd(&st2[c],s0);      unsafeAtomicAdd(&st2[c+1],s1);
  unsafeAtomicAdd(&st2[HD+c],q0);   unsafeAtomicAdd(&st2[HD+c+1],q1);
}
__global__ void k_bn_final(const unsigned* __restrict__ Tu, const float* __restrict__ g,
    const float* __restrict__ bb, const float* __restrict__ st, float* __restrict__ X)
{
  long i = (long)blockIdx.x*blockDim.x + threadIdx.x;
  if (i >= (long)NN*256) return;
  int c = ((int)(i & 255)) << 1;
  const float inv_n = 1.f/(float)NN;
  float mu0 = st[c]*inv_n, mu1 = st[c+1]*inv_n;
  float var0 = st[HD+c]*inv_n - mu0*mu0;
  float var1 = st[HD+c+1]*inv_n - mu1*mu1;
  float sc0 = g[c]*rsqrtf(var0+BN_EPS), sc1 = g[c+1]*rsqrtf(var1+BN_EPS);
  float sh0 = bb[c] - mu0*sc0, sh1 = bb[c+1] - mu1*sc1;
  unsigned u = Tu[i];
  float2 o;
  o.x = fmaf(h2fu(u&0xFFFF), sc0, sh0);
  o.y = fmaf(h2fu(u>>16),   sc1, sh1);
  *(float2*)(X + (i<<1)) = o;
}

// ---------------- head ----------------
__global__ void k_lin2(const unsigned short* __restrict__ Z1, const float* __restrict__ w2,
    const float* __restrict__ b2, const int* __restrict__ mask, float* __restrict__ z2)
{
  int i = blockIdx.x*4 + (threadIdx.x >> 6);
  int lane = threadIdx.x & 63;
  if (i >= NN) return;
  float v = h2fu(Z1[(size_t)i*HIDN + lane]) * w2[lane];
  #pragma unroll
  for (int off=32; off>=1; off>>=1) v += __shfl_xor(v, off);
  if (lane == 0){
    float t = leaky(v + b2[0]);
    z2[i] = mask[i] ? t : 0.f;
  }
}
__device__ __forceinline__ unsigned fkey(float f){
  unsigned u = __float_as_uint(f);
  return (u & 0x80000000u) ? ~u : (u | 0x80000000u);
}
__device__ __forceinline__ float funkey(unsigned k){
  unsigned u = (k & 0x80000000u) ? (k & 0x7fffffffu) : ~k;
  return __uint_as_float(u);
}
__global__ void k_minmax(const float* __restrict__ z2, const int* __restrict__ batch,
                         unsigned* __restrict__ mx, unsigned* __restrict__ mn){
  int i = blockIdx.x*blockDim.x + threadIdx.x;
  if (i < NN){
    unsigned k = fkey(z2[i]); int g = batch[i];
    atomicMax(&mx[g], k); atomicMin(&mn[g], k);
  }
}
__global__ void k_final(const float* __restrict__ z2, const int* __restrict__ batch,
                        const unsigned* __restrict__ mx, const unsigned* __restrict__ mn,
                        float* __restrict__ out){
  int i = blockIdx.x*blockDim.x + threadIdx.x;
  if (i < NN){
    int g = batch[i];
    float bmax = funkey(mx[g]), bmin = funkey(mn[g]);
    out[i] = (z2[i] - bmin) / ((bmax + 1e-6f) - bmin);
  }
}

extern "C" void kernel_launch(void* const* d_in, const int* in_sizes, int n_in,
                              void* d_out, int out_size, void* d_ws, size_t ws_size,
                              hipStream_t stream)
{
  const float* x      = (const float*)d_in[0];
  const int*   ei     = (const int*)d_in[1];
  const int*   src    = ei;
  const int*   dst    = ei + NE;
  const int*   batch  = (const int*)d_in[2];
  const float* c1_w1  = (const float*)d_in[3];
  const float* c1_b1  = (const float*)d_in[4];
  const float* c1_w2  = (const float*)d_in[5];
  const float* c1_b2  = (const float*)d_in[6];
  const float* c1_bng = (const float*)d_in[7];
  const float* c1_bnb = (const float*)d_in[8];
  const float* eps1   = (const float*)d_in[9];
  const float* bn1_g  = (const float*)d_in[10];
  const float* bn1_b  = (const float*)d_in[11];
  const float* cw1    = (const float*)d_in[12];
  const float* cb1    = (const float*)d_in[13];
  const float* cw2    = (const float*)d_in[14];
  const float* cb2    = (const float*)d_in[15];
  const float* cbn_g  = (const float*)d_in[16];
  const float* cbn_b  = (const float*)d_in[17];
  const float* ceps   = (const float*)d_in[18];
  const float* bns_g  = (const float*)d_in[19];
  const float* bns_b  = (const float*)d_in[20];
  const float* l1_w   = (const float*)d_in[21];
  const float* l1_b   = (const float*)d_in[22];
  const float* l2_w   = (const float*)d_in[23];
  const float* l2_b   = (const float*)d_in[24];
  float* out = (float*)d_out;

  const size_t NH = (size_t)NN*HD;
  float* X = (float*)d_ws;                        // fp32 NH (residual stream)
  unsigned short* A = (unsigned short*)(X + NH);  // fp16 NH
  unsigned short* B = A + NH;                     // fp16 NH
  float* h0   = (float*)(B + NH);                 // NN
  float* invs = h0 + NN;                          // NN
  float* z2   = invs + NN;                        // NN
  float* st1  = z2 + NN;                          // 1024
  float* st2  = st1 + 1024;                       // 1024
  int* counts = (int*)(st2 + 1024);               // 64
  unsigned* mx = (unsigned*)(counts + 64);        // 64
  unsigned* mn = mx + 64;                         // 64
  int* deg  = (int*)(mn + 64);                    // NN
  int* off  = deg + NN;                           // NN
  int* cur  = off + NN;                           // NN
  int* srcs = cur + NN;                           // NE
  int* m[5];
  m[0] = srcs + NE;
  for (int k=1;k<5;k++) m[k] = m[k-1] + NN;
  unsigned short* wt[7];                          // 7 x 512*512 fp16 transposed weights
  wt[0] = (unsigned short*)(m[4] + NN);
  for (int k=1;k<7;k++) wt[k] = wt[k-1] + HD*HD;

  unsigned* Au = (unsigned*)A;
  unsigned* Bu = (unsigned*)B;

  const int TPB = 256;
  dim3 gN((NN+TPB-1)/TPB);
  dim3 gE((NE+TPB-1)/TPB);
  dim3 gNH((unsigned)((NH + TPB-1)/TPB));
  dim3 gNH2((unsigned)((NH/2 + TPB-1)/TPB));
  dim3 gmfma((NN+127)/128, HD/128);
  dim3 gtr(HD/32, HD/32);

  // setup
  hipMemsetAsync(counts, 0, 64*sizeof(int), stream);
  k_counts<<<gN, TPB, 0, stream>>>(batch, counts);
  k_invs_mask0<<<gN, TPB, 0, stream>>>(batch, counts, x, invs, m[0]);
  for (int k=1;k<5;k++){
    k_mask_copy<<<gN,TPB,0,stream>>>(m[k-1], m[k]);
    k_mask_prop<<<gE,TPB,0,stream>>>(m[k-1], m[k], src, dst);
  }
  // CSR by dst
  hipMemsetAsync(deg, 0, NN*sizeof(int), stream);
  k_deg<<<gE,TPB,0,stream>>>(dst, deg);
  k_scan<<<1,1024,0,stream>>>(deg, off, cur);
  k_scatter<<<gE,TPB,0,stream>>>(src, dst, cur, srcs);
  // weight prep (fp16 transposed)
  k_w2ht<<<gtr,256,0,stream>>>(c1_w2, wt[0], HD, HD);
  for (int i=0;i<3;i++){
    k_w2ht<<<gtr,256,0,stream>>>(cw1 + (size_t)i*HD*HD, wt[1+i], HD, HD);
    k_w2ht<<<gtr,256,0,stream>>>(cw2 + (size_t)i*HD*HD, wt[4+i], HD, HD);
  }

  // conv1: H1->A, mfma gemm->B, bn_conv+leaky+scale->A(T), bn1->X
  k_sagg_csr<<<gN,TPB,0,stream>>>(x, off, deg, srcs, eps1, h0);
  k_conv1_h1<<<gNH,TPB,0,stream>>>(h0, c1_w1, c1_b1, A);
  k_gemm_mfma<<<gmfma,256,0,stream>>>((const _Float16*)A, (const _Float16*)wt[0], c1_b2, (_Float16*)B, NN);
  hipMemsetAsync(st1, 0, 1024*sizeof(float), stream);
  k_bn_stats<<<512,256,0,stream>>>(Bu, st1);
  hipMemsetAsync(st2, 0, 1024*sizeof(float), stream);
  k_bn_apply_stats<false><<<512,256,0,stream>>>(Bu, c1_bng, c1_bnb, st1, nullptr, m[1], invs, Au, st2);
  k_bn_final<<<gNH2,TPB,0,stream>>>(Au, bn1_g, bn1_b, st2, X);

  // mid layers: agg X->A, g1 A->B, g2 B->A, stats A, apply (A,resid X)->B, final B->X
  for (int i=0;i<3;i++){
    k_agg_csr<<<NN,128,0,stream>>>(X, off, deg, srcs, ceps+i, A);
    k_gemm_mfma<<<gmfma,256,0,stream>>>((const _Float16*)A, (const _Float16*)wt[1+i], cb1 + (size_t)i*HD, (_Float16*)B, NN);
    k_gemm_mfma<<<gmfma,256,0,stream>>>((const _Float16*)B, (const _Float16*)wt[4+i], cb2 + (size_t)i*HD, (_Float16*)A, NN);
    hipMemsetAsync(st1, 0, 1024*sizeof(float), stream);
    k_bn_stats<<<512,256,0,stream>>>(Au, st1);
    hipMemsetAsync(st2, 0, 1024*sizeof(float), stream);
    k_bn_apply_stats<true><<<512,256,0,stream>>>(Au, cbn_g + (size_t)i*HD, cbn_b + (size_t)i*HD, st1, X, m[i+2], invs, Bu, st2);
    k_bn_final<<<gNH2,TPB,0,stream>>>(Bu, bns_g + (size_t)i*HD, bns_b + (size_t)i*HD, st2, X);
  }

  // head: lin1 (fp32 input X, leaky+mask) -> A, lin2 -> z2, min/max, normalize
  dim3 glin1((NN+63)/64, 1);
  k_gemm_v<2,true><<<glin1,256,0,stream>>>(X, l1_w, l1_b, m[4], A, NN, HIDN);
  k_lin2<<<(NN+3)/4,256,0,stream>>>(A, l2_w, l2_b, m[4], z2);
  hipMemsetAsync(mx, 0x00, 64*sizeof(unsigned), stream);
  hipMemsetAsync(mn, 0xFF, 64*sizeof(unsigned), stream);
  k_minmax<<<gN,TPB,0,stream>>>(z2, batch, mx, mn);
  k_final<<<gN,TPB,0,stream>>>(z2, batch, mx, mn, out);
}

// Round 5
// 1980.641 us; speedup vs baseline: 2.1034x; 1.0493x over previous
//
#include <hip/hip_runtime.h>
#include <hip/hip_fp16.h>

#define NN 50000
#define NE 150000
#define HD 512
#define HIDN 64
#define BN_EPS 1e-5f
#define SLOPE 0.01f

typedef _Float16 half8 __attribute__((ext_vector_type(8)));
typedef float floatx4 __attribute__((ext_vector_type(4)));

#define GLDS16(g, l) __builtin_amdgcn_global_load_lds( \
    (const __attribute__((address_space(1))) void*)(g), \
    (__attribute__((address_space(3))) void*)(l), 16, 0, 0)

__device__ __forceinline__ float leaky(float v){ return v > 0.f ? v : SLOPE*v; }
__device__ __forceinline__ float h2fu(unsigned short u){ return __half2float(__ushort_as_half(u)); }
__device__ __forceinline__ unsigned short f2hu(float f){ return __half_as_ushort(__float2half(f)); }
__device__ __forceinline__ unsigned packh2(float a, float b){
  return (unsigned)f2hu(a) | ((unsigned)f2hu(b) << 16);
}

// ---------------- setup ----------------
__global__ void k_counts(const int* __restrict__ batch, int* __restrict__ counts){
  int i = blockIdx.x*blockDim.x + threadIdx.x;
  if (i < NN) atomicAdd(&counts[batch[i]], 1);
}
__global__ void k_invs_mask0(const int* __restrict__ batch, const int* __restrict__ counts,
                             const float* __restrict__ x, float* __restrict__ invs, int* __restrict__ m0){
  int i = blockIdx.x*blockDim.x + threadIdx.x;
  if (i < NN){
    invs[i] = rsqrtf((float)counts[batch[i]]);
    m0[i] = (fabsf(x[i]) > 0.f) ? 1 : 0;
  }
}
__global__ void k_mask_copy(const int* __restrict__ a, int* __restrict__ b){
  int i = blockIdx.x*blockDim.x + threadIdx.x;
  if (i < NN) b[i] = a[i];
}
__global__ void k_mask_prop(const int* __restrict__ mi, int* __restrict__ mo,
                            const int* __restrict__ src, const int* __restrict__ dst){
  int e = blockIdx.x*blockDim.x + threadIdx.x;
  if (e < NE){ if (mi[src[e]]) atomicOr(&mo[dst[e]], 1); }
}

// ---------------- CSR build (by dst) ----------------
__global__ void k_deg(const int* __restrict__ dst, int* __restrict__ deg){
  int e = blockIdx.x*blockDim.x + threadIdx.x;
  if (e < NE) atomicAdd(&deg[dst[e]], 1);
}
#define SCAN_CHUNK 49  // 1024*49 = 50176 >= NN
__global__ void k_scan(const int* __restrict__ deg, int* __restrict__ off, int* __restrict__ cur){
  __shared__ int part[1024];
  int t = threadIdx.x;
  int base = t * SCAN_CHUNK;
  int s = 0;
  for (int j = 0; j < SCAN_CHUNK; j++){ int i = base + j; if (i < NN) s += deg[i]; }
  part[t] = s;
  __syncthreads();
  for (int d = 1; d < 1024; d <<= 1){
    int add = (t >= d) ? part[t - d] : 0;
    __syncthreads();
    part[t] += add;
    __syncthreads();
  }
  int run = part[t] - s;
  for (int j = 0; j < SCAN_CHUNK; j++){
    int i = base + j;
    if (i < NN){ off[i] = run; cur[i] = run; run += deg[i]; }
  }
}
__global__ void k_scatter(const int* __restrict__ src, const int* __restrict__ dst,
                          int* __restrict__ cur, int* __restrict__ srcs){
  int e = blockIdx.x*blockDim.x + threadIdx.x;
  if (e < NE){
    int pos = atomicAdd(&cur[dst[e]], 1);
    srcs[pos] = src[e];
  }
}

// ---------------- weight prep: Wt[n][k] fp16 = W[k][n] fp32 ----------------
__global__ void k_w2ht(const float* __restrict__ W, unsigned short* __restrict__ Wt, int K, int N){
  __shared__ float t[32][33];
  int kb = blockIdx.x*32, nb = blockIdx.y*32;
  int tx = threadIdx.x & 31, ty = threadIdx.x >> 5;   // 32 x 8
  for (int r = 0; r < 32; r += 8)
    t[ty+r][tx] = W[(size_t)(kb+ty+r)*N + nb+tx];
  __syncthreads();
  for (int r = 0; r < 32; r += 8)
    Wt[(size_t)(nb+ty+r)*K + kb+tx] = f2hu(t[tx][ty+r]);
}

// ---------------- conv1 front ----------------
__global__ void k_sagg_csr(const float* __restrict__ x, const int* __restrict__ off,
                           const int* __restrict__ deg, const int* __restrict__ srcs,
                           const float* __restrict__ epsp, float* __restrict__ h0){
  int i = blockIdx.x*blockDim.x + threadIdx.x;
  if (i < NN){
    float s = (1.f + epsp[0]) * x[i];
    int o = off[i], d = deg[i];
    for (int j = 0; j < d; j++) s += x[srcs[o + j]];
    h0[i] = s;
  }
}
__global__ void k_conv1_h1(const float* __restrict__ h0, const float* __restrict__ w1,
                           const float* __restrict__ b1, unsigned short* __restrict__ C){
  long idx = (long)blockIdx.x*blockDim.x + threadIdx.x;
  if (idx >= (long)NN*HD) return;
  int i = (int)(idx >> 9), c = (int)(idx & (HD-1));
  float v = fmaf(h0[i], w1[c], b1[c]);
  C[idx] = f2hu(v > 0.f ? v : 0.f);
}

// ---------------- gather+combine: G[i] = (1+eps)*Xh[i] + sum Xh[src], fp16 in/out, fp32 acc ----------------
__global__ void k_agg_csr(const _Float16* __restrict__ Xh, const int* __restrict__ off,
                          const int* __restrict__ deg, const int* __restrict__ srcs,
                          const float* __restrict__ epsp, _Float16* __restrict__ G){
  int i = blockIdx.x;
  int t = threadIdx.x;          // 64 threads, 8 channels each
  const half8* Xv = (const half8*)Xh;
  half8 p = Xv[(size_t)i*64 + t];
  float ep = 1.f + epsp[0];
  float acc[8];
  #pragma unroll
  for (int k = 0; k < 8; k++) acc[k] = (float)p[k] * ep;
  int o = off[i], d = deg[i];
  for (int j = 0; j < d; j++){
    int s = srcs[o + j];
    half8 q = Xv[(size_t)s*64 + t];
    #pragma unroll
    for (int k = 0; k < 8; k++) acc[k] += (float)q[k];
  }
  half8 r;
  #pragma unroll
  for (int k = 0; k < 8; k++) r[k] = (_Float16)acc[k];
  ((half8*)G)[(size_t)i*64 + t] = r;
}

// ---------------- MFMA GEMM: C[Mx512](fp16) = relu(A[Mx512] @ W + b), optional fused BN stats ----------------
// A row-major fp16, Wt[n][k] fp16. 128x128 tile, 4 waves x (64x64), BK=64,
// global_load_lds staging with XOR k-chunk swizzle (phys = logical ^ (row&7)).
template<bool STATS>
__global__ __launch_bounds__(256) void k_gemm_mfma(const _Float16* __restrict__ A,
    const _Float16* __restrict__ Wt, const float* __restrict__ bias,
    _Float16* __restrict__ C, float* __restrict__ st, int M)
{
  __shared__ __attribute__((aligned(16))) _Float16 As[128*64];
  __shared__ __attribute__((aligned(16))) _Float16 Bs[128*64];
  const int tid = threadIdx.x;
  const int m0 = blockIdx.x * 128;
  const int n0 = blockIdx.y * 128;
  const int w = tid >> 6, lane = tid & 63;
  const int wm = (w >> 1) << 6, wn = (w & 1) << 6;
  const int quad = lane >> 4, l16 = lane & 15;
  const int lr = lane >> 3;                 // 0..7 (row within 8-row chunk)
  const int lc = (lane & 7) ^ lr;           // swizzled logical k-chunk to fetch

  floatx4 acc[4][4] = {};

  const _Float16* Ag[4]; const _Float16* Bg[4];
  #pragma unroll
  for (int j = 0; j < 4; j++){
    int c = w*4 + j;                        // 0..15, rows c*8+lr
    int ar = m0 + c*8 + lr; if (ar > M-1) ar = M-1;
    Ag[j] = A  + (size_t)ar*HD + lc*8;
    Bg[j] = Wt + (size_t)(n0 + c*8 + lr)*HD + lc*8;
  }

  for (int kt = 0; kt < HD; kt += 64){
    __syncthreads();
    #pragma unroll
    for (int j = 0; j < 4; j++){
      int c = w*4 + j;
      GLDS16(Ag[j] + kt, &As[c*512]);
      GLDS16(Bg[j] + kt, &Bs[c*512]);
    }
    __syncthreads();
    #pragma unroll
    for (int k0 = 0; k0 < 64; k0 += 32){
      const int Lb = k0 >> 3;               // 0 or 4
      const int pa = ((Lb + quad) ^ (l16 & 7)) * 8;
      half8 af[4], bf[4];
      #pragma unroll
      for (int t4 = 0; t4 < 4; t4++){
        af[t4] = *(const half8*)&As[(wm + t4*16 + l16)*64 + pa];
        bf[t4] = *(const half8*)&Bs[(wn + t4*16 + l16)*64 + pa];
      }
      #pragma unroll
      for (int mi = 0; mi < 4; mi++){
        #pragma unroll
        for (int ni = 0; ni < 4; ni++){
          acc[mi][ni] = __builtin_amdgcn_mfma_f32_16x16x32_f16(af[mi], bf[ni], acc[mi][ni], 0, 0, 0);
        }
      }
    }
  }

  // epilogue: D row = quad*4+reg, col = l16 ; bias+relu+store (+stats)
  float sv[4] = {0,0,0,0}, qv[4] = {0,0,0,0};
  #pragma unroll
  for (int ni = 0; ni < 4; ni++){
    int ccol = n0 + wn + ni*16 + l16;
    float bs = bias[ccol];
    #pragma unroll
    for (int mi = 0; mi < 4; mi++){
      #pragma unroll
      for (int reg = 0; reg < 4; reg++){
        int r = m0 + wm + mi*16 + quad*4 + reg;
        float v = acc[mi][ni][reg] + bs;
        v = v > 0.f ? v : 0.f;
        if (r < M){
          C[(size_t)r*HD + ccol] = (_Float16)v;
          if (STATS){ sv[ni] += v; qv[ni] += v*v; }
        }
      }
    }
  }
  if (STATS){
    #pragma unroll
    for (int ni = 0; ni < 4; ni++){
      float s = sv[ni], q = qv[ni];
      s += __shfl_xor(s, 16); s += __shfl_xor(s, 32);
      q += __shfl_xor(q, 16); q += __shfl_xor(q, 32);
      if (quad == 0){
        int ccol = n0 + wn + ni*16 + l16;
        unsafeAtomicAdd(&st[ccol], s);
        unsafeAtomicAdd(&st[HD+ccol], q);
      }
    }
  }
}

// ---------------- fused head: z2 = leaky((leaky(Xh@W1+b1)*mask)@w2 + b2)*mask, + per-graph min/max ----------------
// BM=128, BN=64=HIDN; 4 waves x (32 rows x 64 cols).
__global__ __launch_bounds__(256) void k_head(const _Float16* __restrict__ Xh,
    const _Float16* __restrict__ W1t, const float* __restrict__ b1,
    const float* __restrict__ w2, const float* __restrict__ b2p,
    const int* __restrict__ mask, const int* __restrict__ batch,
    float* __restrict__ z2, unsigned* __restrict__ mx, unsigned* __restrict__ mn, int M)
{
  __shared__ __attribute__((aligned(16))) _Float16 As[128*64];
  __shared__ __attribute__((aligned(16))) _Float16 Bs[64*64];
  const int tid = threadIdx.x;
  const int m0 = blockIdx.x * 128;
  const int w = tid >> 6, lane = tid & 63;
  const int wm = w << 5;                    // 32 rows per wave
  const int quad = lane >> 4, l16 = lane & 15;
  const int lr = lane >> 3;
  const int lc = (lane & 7) ^ lr;

  floatx4 acc[2][4] = {};

  const _Float16* Ag[4]; const _Float16* Bg[2];
  #pragma unroll
  for (int j = 0; j < 4; j++){
    int c = w*4 + j;                        // rows c*8+lr in 0..127
    int ar = m0 + c*8 + lr; if (ar > M-1) ar = M-1;
    Ag[j] = Xh + (size_t)ar*HD + lc*8;
  }
  #pragma unroll
  for (int j = 0; j < 2; j++){
    int c2 = w*2 + j;                       // rows c2*8+lr in 0..63
    Bg[j] = W1t + (size_t)(c2*8 + lr)*HD + lc*8;
  }

  for (int kt = 0; kt < HD; kt += 64){
    __syncthreads();
    #pragma unroll
    for (int j = 0; j < 4; j++){ int c = w*4 + j;  GLDS16(Ag[j] + kt, &As[c*512]); }
    #pragma unroll
    for (int j = 0; j < 2; j++){ int c2 = w*2 + j; GLDS16(Bg[j] + kt, &Bs[c2*512]); }
    __syncthreads();
    #pragma unroll
    for (int k0 = 0; k0 < 64; k0 += 32){
      const int Lb = k0 >> 3;
      const int pa = ((Lb + quad) ^ (l16 & 7)) * 8;
      half8 af[2], bf[4];
      #pragma unroll
      for (int mi = 0; mi < 2; mi++) af[mi] = *(const half8*)&As[(wm + mi*16 + l16)*64 + pa];
      #pragma unroll
      for (int ni = 0; ni < 4; ni++) bf[ni] = *(const half8*)&Bs[(ni*16 + l16)*64 + pa];
      #pragma unroll
      for (int mi = 0; mi < 2; mi++){
        #pragma unroll
        for (int ni = 0; ni < 4; ni++){
          acc[mi][ni] = __builtin_amdgcn_mfma_f32_16x16x32_f16(af[mi], bf[ni], acc[mi][ni], 0, 0, 0);
        }
      }
    }
  }

  float b1v[4], w2v[4];
  #pragma unroll
  for (int ni = 0; ni < 4; ni++){ b1v[ni] = b1[ni*16 + l16]; w2v[ni] = w2[ni*16 + l16]; }
  const float b2 = b2p[0];
  #pragma unroll
  for (int mi = 0; mi < 2; mi++){
    #pragma unroll
    for (int reg = 0; reg < 4; reg++){
      int r = m0 + wm + mi*16 + quad*4 + reg;
      bool ok = r < M;
      float mk = (ok && mask[r]) ? 1.f : 0.f;
      float t = 0.f;
      #pragma unroll
      for (int ni = 0; ni < 4; ni++){
        float v = leaky(acc[mi][ni][reg] + b1v[ni]) * mk;
        t += v * w2v[ni];
      }
      t += __shfl_xor(t, 1); t += __shfl_xor(t, 2);
      t += __shfl_xor(t, 4); t += __shfl_xor(t, 8);
      if (l16 == 0 && ok){
        float zv = leaky(t + b2) * mk;
        z2[r] = zv;
        unsigned u = __float_as_uint(zv);
        unsigned key = (u & 0x80000000u) ? ~u : (u | 0x80000000u);
        int g = batch[r];
        atomicMax(&mx[g], key); atomicMin(&mn[g], key);
      }
    }
  }
}

// ---------------- BN apply (fp16 data, fp32 stats) ----------------
// T = (resid(fp16) + leaky(bn(Hin fp16)))*mask*invs -> T fp16 ; stats of T -> st2
template<bool RESID>
__global__ void k_bn_apply_stats(const unsigned* __restrict__ Hu, const float* __restrict__ g,
    const float* __restrict__ bb, const float* __restrict__ st,
    const unsigned* __restrict__ Ru, const int* __restrict__ mask, const float* __restrict__ invs,
    unsigned* __restrict__ Tu, float* __restrict__ st2)
{
  int tid = threadIdx.x; int c = tid<<1;
  const float inv_n = 1.f/(float)NN;
  float mu0 = st[c]*inv_n, mu1 = st[c+1]*inv_n;
  float var0 = st[HD+c]*inv_n - mu0*mu0;
  float var1 = st[HD+c+1]*inv_n - mu1*mu1;
  float sc0 = g[c]*rsqrtf(var0+BN_EPS), sc1 = g[c+1]*rsqrtf(var1+BN_EPS);
  float sh0 = bb[c] - mu0*sc0, sh1 = bb[c+1] - mu1*sc1;
  float s0=0,s1=0,q0=0,q1=0;
  for (int r = blockIdx.x; r < NN; r += gridDim.x){
    unsigned u = Hu[(size_t)r*256 + tid];
    float v0 = leaky(fmaf(h2fu(u&0xFFFF), sc0, sh0));
    float v1 = leaky(fmaf(h2fu(u>>16),   sc1, sh1));
    if (RESID){
      unsigned ru = Ru[(size_t)r*256 + tid];
      v0 += h2fu(ru&0xFFFF); v1 += h2fu(ru>>16);
    }
    float ww = mask[r] ? invs[r] : 0.f;
    v0 *= ww; v1 *= ww;
    Tu[(size_t)r*256 + tid] = packh2(v0, v1);
    s0+=v0; s1+=v1; q0+=v0*v0; q1+=v1*v1;
  }
  unsafeAtomicAdd(&st2[c],s0);      unsafeAtomicAdd(&st2[c+1],s1);
  unsafeAtomicAdd(&st2[HD+c],q0);   unsafeAtomicAdd(&st2[HD+c+1],q1);
}
// Xh(fp16) = bn(T fp16) with stats st
__global__ void k_bn_final(const unsigned* __restrict__ Tu, const float* __restrict__ g,
    const float* __restrict__ bb, const float* __restrict__ st, unsigned* __restrict__ Xhu)
{
  long i = (long)blockIdx.x*blockDim.x + threadIdx.x;
  if (i >= (long)NN*256) return;
  int c = ((int)(i & 255)) << 1;
  const float inv_n = 1.f/(float)NN;
  float mu0 = st[c]*inv_n, mu1 = st[c+1]*inv_n;
  float var0 = st[HD+c]*inv_n - mu0*mu0;
  float var1 = st[HD+c+1]*inv_n - mu1*mu1;
  float sc0 = g[c]*rsqrtf(var0+BN_EPS), sc1 = g[c+1]*rsqrtf(var1+BN_EPS);
  float sh0 = bb[c] - mu0*sc0, sh1 = bb[c+1] - mu1*sc1;
  unsigned u = Tu[i];
  Xhu[i] = packh2(fmaf(h2fu(u&0xFFFF), sc0, sh0), fmaf(h2fu(u>>16), sc1, sh1));
}

// ---------------- final normalize ----------------
__device__ __forceinline__ float funkey(unsigned k){
  unsigned u = (k & 0x80000000u) ? (k & 0x7fffffffu) : ~k;
  return __uint_as_float(u);
}
__global__ void k_final(const float* __restrict__ z2, const int* __restrict__ batch,
                        const unsigned* __restrict__ mx, const unsigned* __restrict__ mn,
                        float* __restrict__ out){
  int i = blockIdx.x*blockDim.x + threadIdx.x;
  if (i < NN){
    int g = batch[i];
    float bmax = funkey(mx[g]), bmin = funkey(mn[g]);
    out[i] = (z2[i] - bmin) / ((bmax + 1e-6f) - bmin);
  }
}

extern "C" void kernel_launch(void* const* d_in, const int* in_sizes, int n_in,
                              void* d_out, int out_size, void* d_ws, size_t ws_size,
                              hipStream_t stream)
{
  const float* x      = (const float*)d_in[0];
  const int*   ei     = (const int*)d_in[1];
  const int*   src    = ei;
  const int*   dst    = ei + NE;
  const int*   batch  = (const int*)d_in[2];
  const float* c1_w1  = (const float*)d_in[3];
  const float* c1_b1  = (const float*)d_in[4];
  const float* c1_w2  = (const float*)d_in[5];
  const float* c1_b2  = (const float*)d_in[6];
  const float* c1_bng = (const float*)d_in[7];
  const float* c1_bnb = (const float*)d_in[8];
  const float* eps1   = (const float*)d_in[9];
  const float* bn1_g  = (const float*)d_in[10];
  const float* bn1_b  = (const float*)d_in[11];
  const float* cw1    = (const float*)d_in[12];
  const float* cb1    = (const float*)d_in[13];
  const float* cw2    = (const float*)d_in[14];
  const float* cb2    = (const float*)d_in[15];
  const float* cbn_g  = (const float*)d_in[16];
  const float* cbn_b  = (const float*)d_in[17];
  const float* ceps   = (const float*)d_in[18];
  const float* bns_g  = (const float*)d_in[19];
  const float* bns_b  = (const float*)d_in[20];
  const float* l1_w   = (const float*)d_in[21];
  const float* l1_b   = (const float*)d_in[22];
  const float* l2_w   = (const float*)d_in[23];
  const float* l2_b   = (const float*)d_in[24];
  float* out = (float*)d_out;

  const size_t NH = (size_t)NN*HD;
  unsigned short* Xh = (unsigned short*)d_ws;     // fp16 NH (residual stream)
  unsigned short* A  = Xh + NH;                   // fp16 NH
  unsigned short* B  = A + NH;                    // fp16 NH
  float* h0   = (float*)(B + NH);                 // NN
  float* invs = h0 + NN;                          // NN
  float* z2   = invs + NN;                        // NN
  float* st1  = z2 + NN;                          // 1024
  float* st2  = st1 + 1024;                       // 1024
  int* counts = (int*)(st2 + 1024);               // 64
  unsigned* mx = (unsigned*)(counts + 64);        // 64
  unsigned* mn = mx + 64;                         // 64
  int* deg  = (int*)(mn + 64);                    // NN
  int* off  = deg + NN;                           // NN
  int* cur  = off + NN;                           // NN
  int* srcs = cur + NN;                           // NE
  int* m[5];
  m[0] = srcs + NE;
  for (int k=1;k<5;k++) m[k] = m[k-1] + NN;
  unsigned short* wt[7];                          // 7 x 512*512 fp16 transposed weights
  wt[0] = (unsigned short*)(m[4] + NN);
  for (int k=1;k<7;k++) wt[k] = wt[k-1] + HD*HD;
  unsigned short* w1t = wt[6] + HD*HD;            // 64*512 fp16 lin1 transposed

  unsigned* Xhu = (unsigned*)Xh;
  unsigned* Au = (unsigned*)A;
  unsigned* Bu = (unsigned*)B;

  const int TPB = 256;
  dim3 gN((NN+TPB-1)/TPB);
  dim3 gE((NE+TPB-1)/TPB);
  dim3 gNH((unsigned)((NH + TPB-1)/TPB));
  dim3 gNH2((unsigned)((NH/2 + TPB-1)/TPB));
  dim3 gmfma((NN+127)/128, HD/128);
  dim3 gtr(HD/32, HD/32);
  dim3 ghead((NN+127)/128);

  // setup
  hipMemsetAsync(counts, 0, 64*sizeof(int), stream);
  k_counts<<<gN, TPB, 0, stream>>>(batch, counts);
  k_invs_mask0<<<gN, TPB, 0, stream>>>(batch, counts, x, invs, m[0]);
  for (int k=1;k<5;k++){
    k_mask_copy<<<gN,TPB,0,stream>>>(m[k-1], m[k]);
    k_mask_prop<<<gE,TPB,0,stream>>>(m[k-1], m[k], src, dst);
  }
  // CSR by dst
  hipMemsetAsync(deg, 0, NN*sizeof(int), stream);
  k_deg<<<gE,TPB,0,stream>>>(dst, deg);
  k_scan<<<1,1024,0,stream>>>(deg, off, cur);
  k_scatter<<<gE,TPB,0,stream>>>(src, dst, cur, srcs);
  // weight prep (fp16 transposed)
  k_w2ht<<<gtr,256,0,stream>>>(c1_w2, wt[0], HD, HD);
  for (int i=0;i<3;i++){
    k_w2ht<<<gtr,256,0,stream>>>(cw1 + (size_t)i*HD*HD, wt[1+i], HD, HD);
    k_w2ht<<<gtr,256,0,stream>>>(cw2 + (size_t)i*HD*HD, wt[4+i], HD, HD);
  }
  k_w2ht<<<dim3(HD/32, HIDN/32),256,0,stream>>>(l1_w, w1t, HD, HIDN);

  // conv1: h1->A, gemm(+stats)->B, apply->A(T), final->Xh
  k_sagg_csr<<<gN,TPB,0,stream>>>(x, off, deg, srcs, eps1, h0);
  k_conv1_h1<<<gNH,TPB,0,stream>>>(h0, c1_w1, c1_b1, A);
  hipMemsetAsync(st1, 0, 1024*sizeof(float), stream);
  k_gemm_mfma<true><<<gmfma,256,0,stream>>>((const _Float16*)A, (const _Float16*)wt[0], c1_b2, (_Float16*)B, st1, NN);
  hipMemsetAsync(st2, 0, 1024*sizeof(float), stream);
  k_bn_apply_stats<false><<<512,256,0,stream>>>(Bu, c1_bng, c1_bnb, st1, nullptr, m[1], invs, Au, st2);
  k_bn_final<<<gNH2,TPB,0,stream>>>(Au, bn1_g, bn1_b, st2, Xhu);

  // mid layers: agg Xh->A, g1 A->B, g2(+stats) B->A, apply (A, resid Xh)->B, final B->Xh
  for (int i=0;i<3;i++){
    k_agg_csr<<<NN,64,0,stream>>>((const _Float16*)Xh, off, deg, srcs, ceps+i, (_Float16*)A);
    k_gemm_mfma<false><<<gmfma,256,0,stream>>>((const _Float16*)A, (const _Float16*)wt[1+i], cb1 + (size_t)i*HD, (_Float16*)B, nullptr, NN);
    hipMemsetAsync(st1, 0, 1024*sizeof(float), stream);
    k_gemm_mfma<true><<<gmfma,256,0,stream>>>((const _Float16*)B, (const _Float16*)wt[4+i], cb2 + (size_t)i*HD, (_Float16*)A, st1, NN);
    hipMemsetAsync(st2, 0, 1024*sizeof(float), stream);
    k_bn_apply_stats<true><<<512,256,0,stream>>>(Au, cbn_g + (size_t)i*HD, cbn_b + (size_t)i*HD, st1, Xhu, m[i+2], invs, Bu, st2);
    k_bn_final<<<gNH2,TPB,0,stream>>>(Bu, bns_g + (size_t)i*HD, bns_b + (size_t)i*HD, st2, Xhu);
  }

  // head: fused lin1+lin2+minmax, then normalize
  hipMemsetAsync(mx, 0x00, 64*sizeof(unsigned), stream);
  hipMemsetAsync(mn, 0xFF, 64*sizeof(unsigned), stream);
  k_head<<<ghead,256,0,stream>>>((const _Float16*)Xh, (const _Float16*)w1t, l1_b, l2_w, l2_b,
                                 m[4], batch, z2, mx, mn, NN);
  k_final<<<gN,TPB,0,stream>>>(z2, batch, mx, mn, out);
}

// Round 6
// 1937.684 us; speedup vs baseline: 2.1500x; 1.0222x over previous
//
#include <hip/hip_runtime.h>
#include <hip/hip_fp16.h>

#define NN 50000
#define NE 150000
#define HD 512
#define HIDN 64
#define BN_EPS 1e-5f
#define SLOPE 0.01f

typedef _Float16 half8 __attribute__((ext_vector_type(8)));
typedef float floatx4 __attribute__((ext_vector_type(4)));

__device__ __forceinline__ float leaky(float v){ return v > 0.f ? v : SLOPE*v; }
__device__ __forceinline__ float h2fu(unsigned short u){ return __half2float(__ushort_as_half(u)); }
__device__ __forceinline__ unsigned short f2hu(float f){ return __half_as_ushort(__float2half(f)); }
__device__ __forceinline__ unsigned packh2(float a, float b){
  return (unsigned)f2hu(a) | ((unsigned)f2hu(b) << 16);
}

// ---------------- setup ----------------
__global__ void k_counts(const int* __restrict__ batch, int* __restrict__ counts){
  int i = blockIdx.x*blockDim.x + threadIdx.x;
  if (i < NN) atomicAdd(&counts[batch[i]], 1);
}
__global__ void k_invs_mask0(const int* __restrict__ batch, const int* __restrict__ counts,
                             const float* __restrict__ x, float* __restrict__ invs, int* __restrict__ m0){
  int i = blockIdx.x*blockDim.x + threadIdx.x;
  if (i < NN){
    invs[i] = rsqrtf((float)counts[batch[i]]);
    m0[i] = (fabsf(x[i]) > 0.f) ? 1 : 0;
  }
}
__global__ void k_mask_copy(const int* __restrict__ a, int* __restrict__ b){
  int i = blockIdx.x*blockDim.x + threadIdx.x;
  if (i < NN) b[i] = a[i];
}
__global__ void k_mask_prop(const int* __restrict__ mi, int* __restrict__ mo,
                            const int* __restrict__ src, const int* __restrict__ dst){
  int e = blockIdx.x*blockDim.x + threadIdx.x;
  if (e < NE){ if (mi[src[e]]) atomicOr(&mo[dst[e]], 1); }
}

// ---------------- CSR build (by dst) ----------------
__global__ void k_deg(const int* __restrict__ dst, int* __restrict__ deg){
  int e = blockIdx.x*blockDim.x + threadIdx.x;
  if (e < NE) atomicAdd(&deg[dst[e]], 1);
}
#define SCAN_CHUNK 49  // 1024*49 = 50176 >= NN
__global__ void k_scan(const int* __restrict__ deg, int* __restrict__ off, int* __restrict__ cur){
  __shared__ int part[1024];
  int t = threadIdx.x;
  int base = t * SCAN_CHUNK;
  int s = 0;
  for (int j = 0; j < SCAN_CHUNK; j++){ int i = base + j; if (i < NN) s += deg[i]; }
  part[t] = s;
  __syncthreads();
  for (int d = 1; d < 1024; d <<= 1){
    int add = (t >= d) ? part[t - d] : 0;
    __syncthreads();
    part[t] += add;
    __syncthreads();
  }
  int run = part[t] - s;
  for (int j = 0; j < SCAN_CHUNK; j++){
    int i = base + j;
    if (i < NN){ off[i] = run; cur[i] = run; run += deg[i]; }
  }
}
__global__ void k_scatter(const int* __restrict__ src, const int* __restrict__ dst,
                          int* __restrict__ cur, int* __restrict__ srcs){
  int e = blockIdx.x*blockDim.x + threadIdx.x;
  if (e < NE){
    int pos = atomicAdd(&cur[dst[e]], 1);
    srcs[pos] = src[e];
  }
}

// ---------------- weight prep: Wt[n][k] fp16 = W[k][n] fp32 ----------------
__global__ void k_w2ht(const float* __restrict__ W, unsigned short* __restrict__ Wt, int K, int N){
  __shared__ float t[32][33];
  int kb = blockIdx.x*32, nb = blockIdx.y*32;
  int tx = threadIdx.x & 31, ty = threadIdx.x >> 5;   // 32 x 8
  for (int r = 0; r < 32; r += 8)
    t[ty+r][tx] = W[(size_t)(kb+ty+r)*N + nb+tx];
  __syncthreads();
  for (int r = 0; r < 32; r += 8)
    Wt[(size_t)(nb+ty+r)*K + kb+tx] = f2hu(t[tx][ty+r]);
}

// ---------------- conv1 front ----------------
__global__ void k_sagg_csr(const float* __restrict__ x, const int* __restrict__ off,
                           const int* __restrict__ deg, const int* __restrict__ srcs,
                           const float* __restrict__ epsp, float* __restrict__ h0){
  int i = blockIdx.x*blockDim.x + threadIdx.x;
  if (i < NN){
    float s = (1.f + epsp[0]) * x[i];
    int o = off[i], d = deg[i];
    for (int j = 0; j < d; j++) s += x[srcs[o + j]];
    h0[i] = s;
  }
}
__global__ void k_conv1_h1(const float* __restrict__ h0, const float* __restrict__ w1,
                           const float* __restrict__ b1, unsigned short* __restrict__ C){
  long idx = (long)blockIdx.x*blockDim.x + threadIdx.x;
  if (idx >= (long)NN*HD) return;
  int i = (int)(idx >> 9), c = (int)(idx & (HD-1));
  float v = fmaf(h0[i], w1[c], b1[c]);
  C[idx] = f2hu(v > 0.f ? v : 0.f);
}

// ---------------- gather+combine: G[i] = (1+eps)*Xh[i] + sum Xh[src], fp16 in/out, fp32 acc ----------------
__global__ void k_agg_csr(const _Float16* __restrict__ Xh, const int* __restrict__ off,
                          const int* __restrict__ deg, const int* __restrict__ srcs,
                          const float* __restrict__ epsp, _Float16* __restrict__ G){
  int i = blockIdx.x;
  int t = threadIdx.x;          // 64 threads, 8 channels each
  const half8* Xv = (const half8*)Xh;
  half8 p = Xv[(size_t)i*64 + t];
  float ep = 1.f + epsp[0];
  float acc[8];
  #pragma unroll
  for (int k = 0; k < 8; k++) acc[k] = (float)p[k] * ep;
  int o = off[i], d = deg[i];
  for (int j = 0; j < d; j++){
    int s = srcs[o + j];
    half8 q = Xv[(size_t)s*64 + t];
    #pragma unroll
    for (int k = 0; k < 8; k++) acc[k] += (float)q[k];
  }
  half8 r;
  #pragma unroll
  for (int k = 0; k < 8; k++) r[k] = (_Float16)acc[k];
  ((half8*)G)[(size_t)i*64 + t] = r;
}

// ---------------- MFMA GEMM: C[Mx512](fp16) = relu(A[Mx512] @ W + b), optional fused BN stats ----------------
// A row-major fp16, Wt[n][k] fp16. 128x128 tile, 4 waves x (64x64), BK=64,
// register staging into padded LDS (PK=72 -> <=2-way bank aliasing, free).
template<bool STATS>
__global__ __launch_bounds__(256) void k_gemm_mfma(const _Float16* __restrict__ A,
    const _Float16* __restrict__ Wt, const float* __restrict__ bias,
    _Float16* __restrict__ C, float* __restrict__ st, int M)
{
  constexpr int PK = 72;
  __shared__ __attribute__((aligned(16))) _Float16 As[128*PK];
  __shared__ __attribute__((aligned(16))) _Float16 Bs[128*PK];
  const int tid = threadIdx.x;
  const int m0 = blockIdx.x * 128;
  const int n0 = blockIdx.y * 128;
  const int w = tid >> 6, lane = tid & 63;
  const int wm = (w >> 1) << 6, wn = (w & 1) << 6;
  const int quad = lane >> 4, l16 = lane & 15;

  floatx4 acc[4][4] = {};

  // staging: 2 threads per row, 64 B (32 halves) each
  const int srow = tid >> 1;                 // 0..127
  const int skoff = (tid & 1) << 5;          // 0 or 32 halves
  const int arow = m0 + srow;
  const bool aok = arow < M;
  const _Float16* Ag = A  + (size_t)arow*HD + skoff;
  const _Float16* Bg = Wt + (size_t)(n0 + srow)*HD + skoff;
  _Float16* Asw = As + srow*PK + skoff;
  _Float16* Bsw = Bs + srow*PK + skoff;

  for (int kt = 0; kt < HD; kt += 64){
    half8 a0={},a1={},a2={},a3={};
    if (aok){
      a0 = *(const half8*)(Ag + kt);      a1 = *(const half8*)(Ag + kt + 8);
      a2 = *(const half8*)(Ag + kt + 16); a3 = *(const half8*)(Ag + kt + 24);
    }
    half8 b0 = *(const half8*)(Bg + kt);      half8 b1 = *(const half8*)(Bg + kt + 8);
    half8 b2 = *(const half8*)(Bg + kt + 16); half8 b3 = *(const half8*)(Bg + kt + 24);
    __syncthreads();
    *(half8*)(Asw)      = a0; *(half8*)(Asw + 8)  = a1;
    *(half8*)(Asw + 16) = a2; *(half8*)(Asw + 24) = a3;
    *(half8*)(Bsw)      = b0; *(half8*)(Bsw + 8)  = b1;
    *(half8*)(Bsw + 16) = b2; *(half8*)(Bsw + 24) = b3;
    __syncthreads();
    #pragma unroll
    for (int k0 = 0; k0 < 64; k0 += 32){
      half8 af[4], bf[4];
      #pragma unroll
      for (int t4 = 0; t4 < 4; t4++){
        af[t4] = *(const half8*)(As + (wm + t4*16 + l16)*PK + k0 + quad*8);
        bf[t4] = *(const half8*)(Bs + (wn + t4*16 + l16)*PK + k0 + quad*8);
      }
      #pragma unroll
      for (int mi = 0; mi < 4; mi++){
        #pragma unroll
        for (int ni = 0; ni < 4; ni++){
          acc[mi][ni] = __builtin_amdgcn_mfma_f32_16x16x32_f16(af[mi], bf[ni], acc[mi][ni], 0, 0, 0);
        }
      }
    }
  }

  // epilogue: D row = quad*4+reg, col = l16 ; bias+relu+store (+stats)
  float sv[4] = {0,0,0,0}, qv[4] = {0,0,0,0};
  #pragma unroll
  for (int ni = 0; ni < 4; ni++){
    int ccol = n0 + wn + ni*16 + l16;
    float bs = bias[ccol];
    #pragma unroll
    for (int mi = 0; mi < 4; mi++){
      #pragma unroll
      for (int reg = 0; reg < 4; reg++){
        int r = m0 + wm + mi*16 + quad*4 + reg;
        float v = acc[mi][ni][reg] + bs;
        v = v > 0.f ? v : 0.f;
        if (r < M){
          C[(size_t)r*HD + ccol] = (_Float16)v;
          if (STATS){ sv[ni] += v; qv[ni] += v*v; }
        }
      }
    }
  }
  if (STATS){
    #pragma unroll
    for (int ni = 0; ni < 4; ni++){
      float s = sv[ni], q = qv[ni];
      s += __shfl_xor(s, 16); s += __shfl_xor(s, 32);
      q += __shfl_xor(q, 16); q += __shfl_xor(q, 32);
      if (quad == 0){
        int ccol = n0 + wn + ni*16 + l16;
        unsafeAtomicAdd(&st[ccol], s);
        unsafeAtomicAdd(&st[HD+ccol], q);
      }
    }
  }
}

// ---------------- fused head: z2 = leaky((leaky(Xh@W1+b1)*mask)@w2 + b2)*mask, + per-graph min/max ----------------
// BM=128, BN=64=HIDN; 4 waves x (32 rows x 64 cols). Register staging, padded LDS.
__global__ __launch_bounds__(256) void k_head(const _Float16* __restrict__ Xh,
    const _Float16* __restrict__ W1t, const float* __restrict__ b1,
    const float* __restrict__ w2, const float* __restrict__ b2p,
    const int* __restrict__ mask, const int* __restrict__ batch,
    float* __restrict__ z2, unsigned* __restrict__ mx, unsigned* __restrict__ mn, int M)
{
  constexpr int PK = 72;
  __shared__ __attribute__((aligned(16))) _Float16 As[128*PK];
  __shared__ __attribute__((aligned(16))) _Float16 Bs[64*PK];
  const int tid = threadIdx.x;
  const int m0 = blockIdx.x * 128;
  const int w = tid >> 6, lane = tid & 63;
  const int wm = w << 5;                    // 32 rows per wave
  const int quad = lane >> 4, l16 = lane & 15;

  floatx4 acc[2][4] = {};

  // A staging: 2 threads/row (rows 0..127), 32 halves each
  const int srow = tid >> 1;
  const int skoff = (tid & 1) << 5;
  const int arow = m0 + srow;
  const bool aok = arow < M;
  const _Float16* Ag = Xh + (size_t)arow*HD + skoff;
  _Float16* Asw = As + srow*PK + skoff;
  // B staging: 4 threads/row (rows 0..63), 16 halves each
  const int brow = tid >> 2;
  const int bkoff = (tid & 3) << 4;
  const _Float16* Bg = W1t + (size_t)brow*HD + bkoff;
  _Float16* Bsw = Bs + brow*PK + bkoff;

  for (int kt = 0; kt < HD; kt += 64){
    half8 a0={},a1={},a2={},a3={};
    if (aok){
      a0 = *(const half8*)(Ag + kt);      a1 = *(const half8*)(Ag + kt + 8);
      a2 = *(const half8*)(Ag + kt + 16); a3 = *(const half8*)(Ag + kt + 24);
    }
    half8 b0 = *(const half8*)(Bg + kt);  half8 b1h = *(const half8*)(Bg + kt + 8);
    __syncthreads();
    *(half8*)(Asw)      = a0; *(half8*)(Asw + 8)  = a1;
    *(half8*)(Asw + 16) = a2; *(half8*)(Asw + 24) = a3;
    *(half8*)(Bsw)      = b0; *(half8*)(Bsw + 8)  = b1h;
    __syncthreads();
    #pragma unroll
    for (int k0 = 0; k0 < 64; k0 += 32){
      half8 af[2], bf[4];
      #pragma unroll
      for (int mi = 0; mi < 2; mi++) af[mi] = *(const half8*)&As[(wm + mi*16 + l16)*PK + k0 + quad*8];
      #pragma unroll
      for (int ni = 0; ni < 4; ni++) bf[ni] = *(const half8*)&Bs[(ni*16 + l16)*PK + k0 + quad*8];
      #pragma unroll
      for (int mi = 0; mi < 2; mi++){
        #pragma unroll
        for (int ni = 0; ni < 4; ni++){
          acc[mi][ni] = __builtin_amdgcn_mfma_f32_16x16x32_f16(af[mi], bf[ni], acc[mi][ni], 0, 0, 0);
        }
      }
    }
  }

  float b1v[4], w2v[4];
  #pragma unroll
  for (int ni = 0; ni < 4; ni++){ b1v[ni] = b1[ni*16 + l16]; w2v[ni] = w2[ni*16 + l16]; }
  const float b2 = b2p[0];
  #pragma unroll
  for (int mi = 0; mi < 2; mi++){
    #pragma unroll
    for (int reg = 0; reg < 4; reg++){
      int r = m0 + wm + mi*16 + quad*4 + reg;
      bool ok = r < M;
      float mk = (ok && mask[r]) ? 1.f : 0.f;
      float t = 0.f;
      #pragma unroll
      for (int ni = 0; ni < 4; ni++){
        float v = leaky(acc[mi][ni][reg] + b1v[ni]) * mk;
        t += v * w2v[ni];
      }
      t += __shfl_xor(t, 1); t += __shfl_xor(t, 2);
      t += __shfl_xor(t, 4); t += __shfl_xor(t, 8);
      if (l16 == 0 && ok){
        float zv = leaky(t + b2) * mk;
        z2[r] = zv;
        unsigned u = __float_as_uint(zv);
        unsigned key = (u & 0x80000000u) ? ~u : (u | 0x80000000u);
        int g = batch[r];
        atomicMax(&mx[g], key); atomicMin(&mn[g], key);
      }
    }
  }
}

// ---------------- BN apply (fp16 data, fp32 stats) ----------------
template<bool RESID>
__global__ void k_bn_apply_stats(const unsigned* __restrict__ Hu, const float* __restrict__ g,
    const float* __restrict__ bb, const float* __restrict__ st,
    const unsigned* __restrict__ Ru, const int* __restrict__ mask, const float* __restrict__ invs,
    unsigned* __restrict__ Tu, float* __restrict__ st2)
{
  int tid = threadIdx.x; int c = tid<<1;
  const float inv_n = 1.f/(float)NN;
  float mu0 = st[c]*inv_n, mu1 = st[c+1]*inv_n;
  float var0 = st[HD+c]*inv_n - mu0*mu0;
  float var1 = st[HD+c+1]*inv_n - mu1*mu1;
  float sc0 = g[c]*rsqrtf(var0+BN_EPS), sc1 = g[c+1]*rsqrtf(var1+BN_EPS);
  float sh0 = bb[c] - mu0*sc0, sh1 = bb[c+1] - mu1*sc1;
  float s0=0,s1=0,q0=0,q1=0;
  for (int r = blockIdx.x; r < NN; r += gridDim.x){
    unsigned u = Hu[(size_t)r*256 + tid];
    float v0 = leaky(fmaf(h2fu(u&0xFFFF), sc0, sh0));
    float v1 = leaky(fmaf(h2fu(u>>16),   sc1, sh1));
    if (RESID){
      unsigned ru = Ru[(size_t)r*256 + tid];
      v0 += h2fu(ru&0xFFFF); v1 += h2fu(ru>>16);
    }
    float ww = mask[r] ? invs[r] : 0.f;
    v0 *= ww; v1 *= ww;
    Tu[(size_t)r*256 + tid] = packh2(v0, v1);
    s0+=v0; s1+=v1; q0+=v0*v0; q1+=v1*v1;
  }
  unsafeAtomicAdd(&st2[c],s0);      unsafeAtomicAdd(&st2[c+1],s1);
  unsafeAtomicAdd(&st2[HD+c],q0);   unsafeAtomicAdd(&st2[HD+c+1],q1);
}
// Xh(fp16) = bn(T fp16) with stats st
__global__ void k_bn_final(const unsigned* __restrict__ Tu, const float* __restrict__ g,
    const float* __restrict__ bb, const float* __restrict__ st, unsigned* __restrict__ Xhu)
{
  long i = (long)blockIdx.x*blockDim.x + threadIdx.x;
  if (i >= (long)NN*256) return;
  int c = ((int)(i & 255)) << 1;
  const float inv_n = 1.f/(float)NN;
  float mu0 = st[c]*inv_n, mu1 = st[c+1]*inv_n;
  float var0 = st[HD+c]*inv_n - mu0*mu0;
  float var1 = st[HD+c+1]*inv_n - mu1*mu1;
  float sc0 = g[c]*rsqrtf(var0+BN_EPS), sc1 = g[c+1]*rsqrtf(var1+BN_EPS);
  float sh0 = bb[c] - mu0*sc0, sh1 = bb[c+1] - mu1*sc1;
  unsigned u = Tu[i];
  Xhu[i] = packh2(fmaf(h2fu(u&0xFFFF), sc0, sh0), fmaf(h2fu(u>>16), sc1, sh1));
}

// ---------------- final normalize ----------------
__device__ __forceinline__ float funkey(unsigned k){
  unsigned u = (k & 0x80000000u) ? (k & 0x7fffffffu) : ~k;
  return __uint_as_float(u);
}
__global__ void k_final(const float* __restrict__ z2, const int* __restrict__ batch,
                        const unsigned* __restrict__ mx, const unsigned* __restrict__ mn,
                        float* __restrict__ out){
  int i = blockIdx.x*blockDim.x + threadIdx.x;
  if (i < NN){
    int g = batch[i];
    float bmax = funkey(mx[g]), bmin = funkey(mn[g]);
    out[i] = (z2[i] - bmin) / ((bmax + 1e-6f) - bmin);
  }
}

extern "C" void kernel_launch(void* const* d_in, const int* in_sizes, int n_in,
                              void* d_out, int out_size, void* d_ws, size_t ws_size,
                              hipStream_t stream)
{
  const float* x      = (const float*)d_in[0];
  const int*   ei     = (const int*)d_in[1];
  const int*   src    = ei;
  const int*   dst    = ei + NE;
  const int*   batch  = (const int*)d_in[2];
  const float* c1_w1  = (const float*)d_in[3];
  const float* c1_b1  = (const float*)d_in[4];
  const float* c1_w2  = (const float*)d_in[5];
  const float* c1_b2  = (const float*)d_in[6];
  const float* c1_bng = (const float*)d_in[7];
  const float* c1_bnb = (const float*)d_in[8];
  const float* eps1   = (const float*)d_in[9];
  const float* bn1_g  = (const float*)d_in[10];
  const float* bn1_b  = (const float*)d_in[11];
  const float* cw1    = (const float*)d_in[12];
  const float* cb1    = (const float*)d_in[13];
  const float* cw2    = (const float*)d_in[14];
  const float* cb2    = (const float*)d_in[15];
  const float* cbn_g  = (const float*)d_in[16];
  const float* cbn_b  = (const float*)d_in[17];
  const float* ceps   = (const float*)d_in[18];
  const float* bns_g  = (const float*)d_in[19];
  const float* bns_b  = (const float*)d_in[20];
  const float* l1_w   = (const float*)d_in[21];
  const float* l1_b   = (const float*)d_in[22];
  const float* l2_w   = (const float*)d_in[23];
  const float* l2_b   = (const float*)d_in[24];
  float* out = (float*)d_out;

  const size_t NH = (size_t)NN*HD;
  unsigned short* Xh = (unsigned short*)d_ws;     // fp16 NH (residual stream)
  unsigned short* A  = Xh + NH;                   // fp16 NH
  unsigned short* B  = A + NH;                    // fp16 NH
  float* h0   = (float*)(B + NH);                 // NN
  float* invs = h0 + NN;                          // NN
  float* z2   = invs + NN;                        // NN
  float* st1  = z2 + NN;                          // 1024
  float* st2  = st1 + 1024;                       // 1024
  int* counts = (int*)(st2 + 1024);               // 64
  unsigned* mx = (unsigned*)(counts + 64);        // 64
  unsigned* mn = mx + 64;                         // 64
  int* deg  = (int*)(mn + 64);                    // NN
  int* off  = deg + NN;                           // NN
  int* cur  = off + NN;                           // NN
  int* srcs = cur + NN;                           // NE
  int* m[5];
  m[0] = srcs + NE;
  for (int k=1;k<5;k++) m[k] = m[k-1] + NN;
  unsigned short* wt[7];                          // 7 x 512*512 fp16 transposed weights
  wt[0] = (unsigned short*)(m[4] + NN);
  for (int k=1;k<7;k++) wt[k] = wt[k-1] + HD*HD;
  unsigned short* w1t = wt[6] + HD*HD;            // 64*512 fp16 lin1 transposed

  unsigned* Xhu = (unsigned*)Xh;
  unsigned* Au = (unsigned*)A;
  unsigned* Bu = (unsigned*)B;

  const int TPB = 256;
  dim3 gN((NN+TPB-1)/TPB);
  dim3 gE((NE+TPB-1)/TPB);
  dim3 gNH((unsigned)((NH + TPB-1)/TPB));
  dim3 gNH2((unsigned)((NH/2 + TPB-1)/TPB));
  dim3 gmfma((NN+127)/128, HD/128);
  dim3 gtr(HD/32, HD/32);
  dim3 ghead((NN+127)/128);

  // setup
  hipMemsetAsync(counts, 0, 64*sizeof(int), stream);
  k_counts<<<gN, TPB, 0, stream>>>(batch, counts);
  k_invs_mask0<<<gN, TPB, 0, stream>>>(batch, counts, x, invs, m[0]);
  for (int k=1;k<5;k++){
    k_mask_copy<<<gN,TPB,0,stream>>>(m[k-1], m[k]);
    k_mask_prop<<<gE,TPB,0,stream>>>(m[k-1], m[k], src, dst);
  }
  // CSR by dst
  hipMemsetAsync(deg, 0, NN*sizeof(int), stream);
  k_deg<<<gE,TPB,0,stream>>>(dst, deg);
  k_scan<<<1,1024,0,stream>>>(deg, off, cur);
  k_scatter<<<gE,TPB,0,stream>>>(src, dst, cur, srcs);
  // weight prep (fp16 transposed)
  k_w2ht<<<gtr,256,0,stream>>>(c1_w2, wt[0], HD, HD);
  for (int i=0;i<3;i++){
    k_w2ht<<<gtr,256,0,stream>>>(cw1 + (size_t)i*HD*HD, wt[1+i], HD, HD);
    k_w2ht<<<gtr,256,0,stream>>>(cw2 + (size_t)i*HD*HD, wt[4+i], HD, HD);
  }
  k_w2ht<<<dim3(HD/32, HIDN/32),256,0,stream>>>(l1_w, w1t, HD, HIDN);

  // conv1: h1->A, gemm(+stats)->B, apply->A(T), final->Xh
  k_sagg_csr<<<gN,TPB,0,stream>>>(x, off, deg, srcs, eps1, h0);
  k_conv1_h1<<<gNH,TPB,0,stream>>>(h0, c1_w1, c1_b1, A);
  hipMemsetAsync(st1, 0, 1024*sizeof(float), stream);
  k_gemm_mfma<true><<<gmfma,256,0,stream>>>((const _Float16*)A, (const _Float16*)wt[0], c1_b2, (_Float16*)B, st1, NN);
  hipMemsetAsync(st2, 0, 1024*sizeof(float), stream);
  k_bn_apply_stats<false><<<512,256,0,stream>>>(Bu, c1_bng, c1_bnb, st1, nullptr, m[1], invs, Au, st2);
  k_bn_final<<<gNH2,TPB,0,stream>>>(Au, bn1_g, bn1_b, st2, Xhu);

  // mid layers: agg Xh->A, g1 A->B, g2(+stats) B->A, apply (A, resid Xh)->B, final B->Xh
  for (int i=0;i<3;i++){
    k_agg_csr<<<NN,64,0,stream>>>((const _Float16*)Xh, off, deg, srcs, ceps+i, (_Float16*)A);
    k_gemm_mfma<false><<<gmfma,256,0,stream>>>((const _Float16*)A, (const _Float16*)wt[1+i], cb1 + (size_t)i*HD, (_Float16*)B, nullptr, NN);
    hipMemsetAsync(st1, 0, 1024*sizeof(float), stream);
    k_gemm_mfma<true><<<gmfma,256,0,stream>>>((const _Float16*)B, (const _Float16*)wt[4+i], cb2 + (size_t)i*HD, (_Float16*)A, st1, NN);
    hipMemsetAsync(st2, 0, 1024*sizeof(float), stream);
    k_bn_apply_stats<true><<<512,256,0,stream>>>(Au, cbn_g + (size_t)i*HD, cbn_b + (size_t)i*HD, st1, Xhu, m[i+2], invs, Bu, st2);
    k_bn_final<<<gNH2,TPB,0,stream>>>(Bu, bns_g + (size_t)i*HD, bns_b + (size_t)i*HD, st2, Xhu);
  }

  // head: fused lin1+lin2+minmax, then normalize
  hipMemsetAsync(mx, 0x00, 64*sizeof(unsigned), stream);
  hipMemsetAsync(mn, 0xFF, 64*sizeof(unsigned), stream);
  k_head<<<ghead,256,0,stream>>>((const _Float16*)Xh, (const _Float16*)w1t, l1_b, l2_w, l2_b,
                                 m[4], batch, z2, mx, mn, NN);
  k_final<<<gN,TPB,0,stream>>>(z2, batch, mx, mn, out);
}

// Round 7
// 1599.637 us; speedup vs baseline: 2.6044x; 1.2113x over previous
//
#include <hip/hip_runtime.h>
#include <hip/hip_fp16.h>

#define NN 50000
#define NE 150000
#define HD 512
#define HIDN 64
#define BN_EPS 1e-5f
#define SLOPE 0.01f

typedef _Float16 half8 __attribute__((ext_vector_type(8)));
typedef float floatx4 __attribute__((ext_vector_type(4)));

__device__ __forceinline__ float leaky(float v){ return v > 0.f ? v : SLOPE*v; }
__device__ __forceinline__ float h2fu(unsigned short u){ return __half2float(__ushort_as_half(u)); }
__device__ __forceinline__ unsigned short f2hu(float f){ return __half_as_ushort(__float2half(f)); }
__device__ __forceinline__ unsigned packh2(float a, float b){
  return (unsigned)f2hu(a) | ((unsigned)f2hu(b) << 16);
}

// ---------------- setup ----------------
__global__ void k_counts(const int* __restrict__ batch, int* __restrict__ counts){
  int i = blockIdx.x*blockDim.x + threadIdx.x;
  if (i < NN) atomicAdd(&counts[batch[i]], 1);
}
__global__ void k_invs_mask0(const int* __restrict__ batch, const int* __restrict__ counts,
                             const float* __restrict__ x, float* __restrict__ invs, int* __restrict__ m0){
  int i = blockIdx.x*blockDim.x + threadIdx.x;
  if (i < NN){
    invs[i] = rsqrtf((float)counts[batch[i]]);
    m0[i] = (fabsf(x[i]) > 0.f) ? 1 : 0;
  }
}
__global__ void k_mask_copy(const int* __restrict__ a, int* __restrict__ b){
  int i = blockIdx.x*blockDim.x + threadIdx.x;
  if (i < NN) b[i] = a[i];
}
__global__ void k_mask_prop(const int* __restrict__ mi, int* __restrict__ mo,
                            const int* __restrict__ src, const int* __restrict__ dst){
  int e = blockIdx.x*blockDim.x + threadIdx.x;
  if (e < NE){ if (mi[src[e]]) atomicOr(&mo[dst[e]], 1); }
}

// ---------------- CSR build (by dst) ----------------
__global__ void k_deg(const int* __restrict__ dst, int* __restrict__ deg){
  int e = blockIdx.x*blockDim.x + threadIdx.x;
  if (e < NE) atomicAdd(&deg[dst[e]], 1);
}
#define SCAN_CHUNK 49  // 1024*49 = 50176 >= NN
__global__ void k_scan(const int* __restrict__ deg, int* __restrict__ off, int* __restrict__ cur){
  __shared__ int part[1024];
  int t = threadIdx.x;
  int base = t * SCAN_CHUNK;
  int s = 0;
  for (int j = 0; j < SCAN_CHUNK; j++){ int i = base + j; if (i < NN) s += deg[i]; }
  part[t] = s;
  __syncthreads();
  for (int d = 1; d < 1024; d <<= 1){
    int add = (t >= d) ? part[t - d] : 0;
    __syncthreads();
    part[t] += add;
    __syncthreads();
  }
  int run = part[t] - s;
  for (int j = 0; j < SCAN_CHUNK; j++){
    int i = base + j;
    if (i < NN){ off[i] = run; cur[i] = run; run += deg[i]; }
  }
}
__global__ void k_scatter(const int* __restrict__ src, const int* __restrict__ dst,
                          int* __restrict__ cur, int* __restrict__ srcs){
  int e = blockIdx.x*blockDim.x + threadIdx.x;
  if (e < NE){
    int pos = atomicAdd(&cur[dst[e]], 1);
    srcs[pos] = src[e];
  }
}

// ---------------- weight prep: Wt[n][k] fp16 = W[k][n] fp32 ----------------
__global__ void k_w2ht(const float* __restrict__ W, unsigned short* __restrict__ Wt, int K, int N){
  __shared__ float t[32][33];
  int kb = blockIdx.x*32, nb = blockIdx.y*32;
  int tx = threadIdx.x & 31, ty = threadIdx.x >> 5;   // 32 x 8
  for (int r = 0; r < 32; r += 8)
    t[ty+r][tx] = W[(size_t)(kb+ty+r)*N + nb+tx];
  __syncthreads();
  for (int r = 0; r < 32; r += 8)
    Wt[(size_t)(nb+ty+r)*K + kb+tx] = f2hu(t[tx][ty+r]);
}

// ---------------- conv1 front ----------------
__global__ void k_sagg_csr(const float* __restrict__ x, const int* __restrict__ off,
                           const int* __restrict__ deg, const int* __restrict__ srcs,
                           const float* __restrict__ epsp, float* __restrict__ h0){
  int i = blockIdx.x*blockDim.x + threadIdx.x;
  if (i < NN){
    float s = (1.f + epsp[0]) * x[i];
    int o = off[i], d = deg[i];
    for (int j = 0; j < d; j++) s += x[srcs[o + j]];
    h0[i] = s;
  }
}
__global__ void k_conv1_h1(const float* __restrict__ h0, const float* __restrict__ w1,
                           const float* __restrict__ b1, unsigned short* __restrict__ C){
  long idx = (long)blockIdx.x*blockDim.x + threadIdx.x;
  if (idx >= (long)NN*HD) return;
  int i = (int)(idx >> 9), c = (int)(idx & (HD-1));
  float v = fmaf(h0[i], w1[c], b1[c]);
  C[idx] = f2hu(v > 0.f ? v : 0.f);
}

// ---------------- gather+combine with on-the-fly BN affine ----------------
// X = sc*T + sh (per channel, from stats st + g,b).
// G[i] = (1+eps)*X[i] + sum X[src] = sc*((1+eps)*T[i] + sum T[src]) + (1+eps+deg)*sh
__global__ void k_agg_csr(const _Float16* __restrict__ T, const int* __restrict__ off,
                          const int* __restrict__ deg, const int* __restrict__ srcs,
                          const float* __restrict__ epsp,
                          const float* __restrict__ st, const float* __restrict__ g,
                          const float* __restrict__ bb, _Float16* __restrict__ G){
  int i = blockIdx.x;
  int t = threadIdx.x;          // 64 threads, 8 channels each
  int c0 = t << 3;
  const float inv_n = 1.f/(float)NN;
  float sc[8], sh[8];
  #pragma unroll
  for (int k = 0; k < 8; k++){
    int c = c0 + k;
    float mu = st[c]*inv_n;
    float var = st[HD+c]*inv_n - mu*mu;
    float s = g[c]*rsqrtf(var+BN_EPS);
    sc[k] = s; sh[k] = bb[c] - mu*s;
  }
  const half8* Tv = (const half8*)T;
  half8 p = Tv[(size_t)i*64 + t];
  float ep = 1.f + epsp[0];
  float acc[8];
  #pragma unroll
  for (int k = 0; k < 8; k++) acc[k] = (float)p[k] * ep;
  int o = off[i], d = deg[i];
  for (int j = 0; j < d; j++){
    int s = srcs[o + j];
    half8 q = Tv[(size_t)s*64 + t];
    #pragma unroll
    for (int k = 0; k < 8; k++) acc[k] += (float)q[k];
  }
  float cnt = ep + (float)d;
  half8 r;
  #pragma unroll
  for (int k = 0; k < 8; k++) r[k] = (_Float16)fmaf(sc[k], acc[k], cnt*sh[k]);
  ((half8*)G)[(size_t)i*64 + t] = r;
}

// ---------------- MFMA GEMM: C[Mx512](fp16) = relu(A[Mx512] @ W + b), optional fused BN stats ----------------
template<bool STATS>
__global__ __launch_bounds__(256) void k_gemm_mfma(const _Float16* __restrict__ A,
    const _Float16* __restrict__ Wt, const float* __restrict__ bias,
    _Float16* __restrict__ C, float* __restrict__ st, int M)
{
  constexpr int PK = 72;
  __shared__ __attribute__((aligned(16))) _Float16 As[128*PK];
  __shared__ __attribute__((aligned(16))) _Float16 Bs[128*PK];
  const int tid = threadIdx.x;
  const int m0 = blockIdx.x * 128;
  const int n0 = blockIdx.y * 128;
  const int w = tid >> 6, lane = tid & 63;
  const int wm = (w >> 1) << 6, wn = (w & 1) << 6;
  const int quad = lane >> 4, l16 = lane & 15;

  floatx4 acc[4][4] = {};

  const int srow = tid >> 1;                 // 0..127
  const int skoff = (tid & 1) << 5;          // 0 or 32 halves
  const int arow = m0 + srow;
  const bool aok = arow < M;
  const _Float16* Ag = A  + (size_t)arow*HD + skoff;
  const _Float16* Bg = Wt + (size_t)(n0 + srow)*HD + skoff;
  _Float16* Asw = As + srow*PK + skoff;
  _Float16* Bsw = Bs + srow*PK + skoff;

  for (int kt = 0; kt < HD; kt += 64){
    half8 a0={},a1={},a2={},a3={};
    if (aok){
      a0 = *(const half8*)(Ag + kt);      a1 = *(const half8*)(Ag + kt + 8);
      a2 = *(const half8*)(Ag + kt + 16); a3 = *(const half8*)(Ag + kt + 24);
    }
    half8 b0 = *(const half8*)(Bg + kt);      half8 b1 = *(const half8*)(Bg + kt + 8);
    half8 b2 = *(const half8*)(Bg + kt + 16); half8 b3 = *(const half8*)(Bg + kt + 24);
    __syncthreads();
    *(half8*)(Asw)      = a0; *(half8*)(Asw + 8)  = a1;
    *(half8*)(Asw + 16) = a2; *(half8*)(Asw + 24) = a3;
    *(half8*)(Bsw)      = b0; *(half8*)(Bsw + 8)  = b1;
    *(half8*)(Bsw + 16) = b2; *(half8*)(Bsw + 24) = b3;
    __syncthreads();
    #pragma unroll
    for (int k0 = 0; k0 < 64; k0 += 32){
      half8 af[4], bf[4];
      #pragma unroll
      for (int t4 = 0; t4 < 4; t4++){
        af[t4] = *(const half8*)(As + (wm + t4*16 + l16)*PK + k0 + quad*8);
        bf[t4] = *(const half8*)(Bs + (wn + t4*16 + l16)*PK + k0 + quad*8);
      }
      #pragma unroll
      for (int mi = 0; mi < 4; mi++){
        #pragma unroll
        for (int ni = 0; ni < 4; ni++){
          acc[mi][ni] = __builtin_amdgcn_mfma_f32_16x16x32_f16(af[mi], bf[ni], acc[mi][ni], 0, 0, 0);
        }
      }
    }
  }

  float sv[4] = {0,0,0,0}, qv[4] = {0,0,0,0};
  #pragma unroll
  for (int ni = 0; ni < 4; ni++){
    int ccol = n0 + wn + ni*16 + l16;
    float bs = bias[ccol];
    #pragma unroll
    for (int mi = 0; mi < 4; mi++){
      #pragma unroll
      for (int reg = 0; reg < 4; reg++){
        int r = m0 + wm + mi*16 + quad*4 + reg;
        float v = acc[mi][ni][reg] + bs;
        v = v > 0.f ? v : 0.f;
        if (r < M){
          C[(size_t)r*HD + ccol] = (_Float16)v;
          if (STATS){ sv[ni] += v; qv[ni] += v*v; }
        }
      }
    }
  }
  if (STATS){
    #pragma unroll
    for (int ni = 0; ni < 4; ni++){
      float s = sv[ni], q = qv[ni];
      s += __shfl_xor(s, 16); s += __shfl_xor(s, 32);
      q += __shfl_xor(q, 16); q += __shfl_xor(q, 32);
      if (quad == 0){
        int ccol = n0 + wn + ni*16 + l16;
        unsafeAtomicAdd(&st[ccol], s);
        unsafeAtomicAdd(&st[HD+ccol], q);
      }
    }
  }
}

// ---------------- fused head with per-block LDS min/max reduction ----------------
__global__ __launch_bounds__(256) void k_head(const _Float16* __restrict__ Xh,
    const _Float16* __restrict__ W1t, const float* __restrict__ b1,
    const float* __restrict__ w2, const float* __restrict__ b2p,
    const int* __restrict__ mask, const int* __restrict__ batch,
    float* __restrict__ z2, unsigned* __restrict__ mx, unsigned* __restrict__ mn, int M)
{
  constexpr int PK = 72;
  __shared__ __attribute__((aligned(16))) _Float16 As[128*PK];
  __shared__ __attribute__((aligned(16))) _Float16 Bs[64*PK];
  __shared__ unsigned smx[64], smn[64];
  const int tid = threadIdx.x;
  const int m0 = blockIdx.x * 128;
  const int w = tid >> 6, lane = tid & 63;
  const int wm = w << 5;
  const int quad = lane >> 4, l16 = lane & 15;

  if (tid < 64){ smx[tid] = 0u; smn[tid] = 0xFFFFFFFFu; }

  floatx4 acc[2][4] = {};

  const int srow = tid >> 1;
  const int skoff = (tid & 1) << 5;
  const int arow = m0 + srow;
  const bool aok = arow < M;
  const _Float16* Ag = Xh + (size_t)arow*HD + skoff;
  _Float16* Asw = As + srow*PK + skoff;
  const int brow = tid >> 2;
  const int bkoff = (tid & 3) << 4;
  const _Float16* Bg = W1t + (size_t)brow*HD + bkoff;
  _Float16* Bsw = Bs + brow*PK + bkoff;

  for (int kt = 0; kt < HD; kt += 64){
    half8 a0={},a1={},a2={},a3={};
    if (aok){
      a0 = *(const half8*)(Ag + kt);      a1 = *(const half8*)(Ag + kt + 8);
      a2 = *(const half8*)(Ag + kt + 16); a3 = *(const half8*)(Ag + kt + 24);
    }
    half8 b0 = *(const half8*)(Bg + kt);  half8 b1h = *(const half8*)(Bg + kt + 8);
    __syncthreads();
    *(half8*)(Asw)      = a0; *(half8*)(Asw + 8)  = a1;
    *(half8*)(Asw + 16) = a2; *(half8*)(Asw + 24) = a3;
    *(half8*)(Bsw)      = b0; *(half8*)(Bsw + 8)  = b1h;
    __syncthreads();
    #pragma unroll
    for (int k0 = 0; k0 < 64; k0 += 32){
      half8 af[2], bf[4];
      #pragma unroll
      for (int mi = 0; mi < 2; mi++) af[mi] = *(const half8*)&As[(wm + mi*16 + l16)*PK + k0 + quad*8];
      #pragma unroll
      for (int ni = 0; ni < 4; ni++) bf[ni] = *(const half8*)&Bs[(ni*16 + l16)*PK + k0 + quad*8];
      #pragma unroll
      for (int mi = 0; mi < 2; mi++){
        #pragma unroll
        for (int ni = 0; ni < 4; ni++){
          acc[mi][ni] = __builtin_amdgcn_mfma_f32_16x16x32_f16(af[mi], bf[ni], acc[mi][ni], 0, 0, 0);
        }
      }
    }
  }

  float b1v[4], w2v[4];
  #pragma unroll
  for (int ni = 0; ni < 4; ni++){ b1v[ni] = b1[ni*16 + l16]; w2v[ni] = w2[ni*16 + l16]; }
  const float b2 = b2p[0];
  #pragma unroll
  for (int mi = 0; mi < 2; mi++){
    #pragma unroll
    for (int reg = 0; reg < 4; reg++){
      int r = m0 + wm + mi*16 + quad*4 + reg;
      bool ok = r < M;
      float mk = (ok && mask[r]) ? 1.f : 0.f;
      float t = 0.f;
      #pragma unroll
      for (int ni = 0; ni < 4; ni++){
        float v = leaky(acc[mi][ni][reg] + b1v[ni]) * mk;
        t += v * w2v[ni];
      }
      t += __shfl_xor(t, 1); t += __shfl_xor(t, 2);
      t += __shfl_xor(t, 4); t += __shfl_xor(t, 8);
      if (l16 == 0 && ok){
        float zv = leaky(t + b2) * mk;
        z2[r] = zv;
        unsigned u = __float_as_uint(zv);
        unsigned key = (u & 0x80000000u) ? ~u : (u | 0x80000000u);
        int gg = batch[r];
        atomicMax(&smx[gg], key); atomicMin(&smn[gg], key);
      }
    }
  }
  __syncthreads();
  if (tid < 64){
    unsigned vx = smx[tid], vn = smn[tid];
    if (vx != 0u)          atomicMax(&mx[tid], vx);
    if (vn != 0xFFFFFFFFu) atomicMin(&mn[tid], vn);
  }
}

// ---------------- BN apply: T = (affineP(T_prev) + leaky(bn(Hin)))*mask*invs ; stats of T -> st2 ----------------
template<bool RESID>
__global__ void k_bn_apply_stats(const unsigned* __restrict__ Hu, const float* __restrict__ g,
    const float* __restrict__ bb, const float* __restrict__ st,
    const unsigned* __restrict__ Pu, const float* __restrict__ stP,
    const float* __restrict__ gP, const float* __restrict__ bP,
    const int* __restrict__ mask, const float* __restrict__ invs,
    unsigned* __restrict__ Tu, float* __restrict__ st2)
{
  int tid = threadIdx.x; int c = tid<<1;
  const float inv_n = 1.f/(float)NN;
  float mu0 = st[c]*inv_n, mu1 = st[c+1]*inv_n;
  float var0 = st[HD+c]*inv_n - mu0*mu0;
  float var1 = st[HD+c+1]*inv_n - mu1*mu1;
  float sc0 = g[c]*rsqrtf(var0+BN_EPS), sc1 = g[c+1]*rsqrtf(var1+BN_EPS);
  float sh0 = bb[c] - mu0*sc0, sh1 = bb[c+1] - mu1*sc1;
  float pc0=0.f, pc1=0.f, ps0=0.f, ps1=0.f;
  if (RESID){
    float muP0 = stP[c]*inv_n, muP1 = stP[c+1]*inv_n;
    float varP0 = stP[HD+c]*inv_n - muP0*muP0;
    float varP1 = stP[HD+c+1]*inv_n - muP1*muP1;
    pc0 = gP[c]*rsqrtf(varP0+BN_EPS); pc1 = gP[c+1]*rsqrtf(varP1+BN_EPS);
    ps0 = bP[c] - muP0*pc0; ps1 = bP[c+1] - muP1*pc1;
  }
  float s0=0,s1=0,q0=0,q1=0;
  for (int r = blockIdx.x; r < NN; r += gridDim.x){
    unsigned u = Hu[(size_t)r*256 + tid];
    float v0 = leaky(fmaf(h2fu(u&0xFFFF), sc0, sh0));
    float v1 = leaky(fmaf(h2fu(u>>16),   sc1, sh1));
    if (RESID){
      unsigned pu = Pu[(size_t)r*256 + tid];
      v0 += fmaf(h2fu(pu&0xFFFF), pc0, ps0);
      v1 += fmaf(h2fu(pu>>16),    pc1, ps1);
    }
    float ww = mask[r] ? invs[r] : 0.f;
    v0 *= ww; v1 *= ww;
    Tu[(size_t)r*256 + tid] = packh2(v0, v1);
    s0+=v0; s1+=v1; q0+=v0*v0; q1+=v1*v1;
  }
  unsafeAtomicAdd(&st2[c],s0);      unsafeAtomicAdd(&st2[c+1],s1);
  unsafeAtomicAdd(&st2[HD+c],q0);   unsafeAtomicAdd(&st2[HD+c+1],q1);
}
// Xh(fp16) = affine(T) with stats st, params g,bb  (used once, before head)
__global__ void k_bn_final(const unsigned* __restrict__ Tu, const float* __restrict__ g,
    const float* __restrict__ bb, const float* __restrict__ st, unsigned* __restrict__ Xhu)
{
  long i = (long)blockIdx.x*blockDim.x + threadIdx.x;
  if (i >= (long)NN*256) return;
  int c = ((int)(i & 255)) << 1;
  const float inv_n = 1.f/(float)NN;
  float mu0 = st[c]*inv_n, mu1 = st[c+1]*inv_n;
  float var0 = st[HD+c]*inv_n - mu0*mu0;
  float var1 = st[HD+c+1]*inv_n - mu1*mu1;
  float sc0 = g[c]*rsqrtf(var0+BN_EPS), sc1 = g[c+1]*rsqrtf(var1+BN_EPS);
  float sh0 = bb[c] - mu0*sc0, sh1 = bb[c+1] - mu1*sc1;
  unsigned u = Tu[i];
  Xhu[i] = packh2(fmaf(h2fu(u&0xFFFF), sc0, sh0), fmaf(h2fu(u>>16), sc1, sh1));
}

// ---------------- final normalize ----------------
__device__ __forceinline__ float funkey(unsigned k){
  unsigned u = (k & 0x80000000u) ? (k & 0x7fffffffu) : ~k;
  return __uint_as_float(u);
}
__global__ void k_final(const float* __restrict__ z2, const int* __restrict__ batch,
                        const unsigned* __restrict__ mx, const unsigned* __restrict__ mn,
                        float* __restrict__ out){
  int i = blockIdx.x*blockDim.x + threadIdx.x;
  if (i < NN){
    int g = batch[i];
    float bmax = funkey(mx[g]), bmin = funkey(mn[g]);
    out[i] = (z2[i] - bmin) / ((bmax + 1e-6f) - bmin);
  }
}

extern "C" void kernel_launch(void* const* d_in, const int* in_sizes, int n_in,
                              void* d_out, int out_size, void* d_ws, size_t ws_size,
                              hipStream_t stream)
{
  const float* x      = (const float*)d_in[0];
  const int*   ei     = (const int*)d_in[1];
  const int*   src    = ei;
  const int*   dst    = ei + NE;
  const int*   batch  = (const int*)d_in[2];
  const float* c1_w1  = (const float*)d_in[3];
  const float* c1_b1  = (const float*)d_in[4];
  const float* c1_w2  = (const float*)d_in[5];
  const float* c1_b2  = (const float*)d_in[6];
  const float* c1_bng = (const float*)d_in[7];
  const float* c1_bnb = (const float*)d_in[8];
  const float* eps1   = (const float*)d_in[9];
  const float* bn1_g  = (const float*)d_in[10];
  const float* bn1_b  = (const float*)d_in[11];
  const float* cw1    = (const float*)d_in[12];
  const float* cb1    = (const float*)d_in[13];
  const float* cw2    = (const float*)d_in[14];
  const float* cb2    = (const float*)d_in[15];
  const float* cbn_g  = (const float*)d_in[16];
  const float* cbn_b  = (const float*)d_in[17];
  const float* ceps   = (const float*)d_in[18];
  const float* bns_g  = (const float*)d_in[19];
  const float* bns_b  = (const float*)d_in[20];
  const float* l1_w   = (const float*)d_in[21];
  const float* l1_b   = (const float*)d_in[22];
  const float* l2_w   = (const float*)d_in[23];
  const float* l2_b   = (const float*)d_in[24];
  float* out = (float*)d_out;

  const size_t NH = (size_t)NN*HD;
  unsigned short* buf0 = (unsigned short*)d_ws;   // fp16 NH
  unsigned short* buf1 = buf0 + NH;               // fp16 NH
  unsigned short* buf2 = buf1 + NH;               // fp16 NH
  float* h0   = (float*)(buf2 + NH);              // NN
  float* invs = h0 + NN;                          // NN
  float* z2   = invs + NN;                        // NN
  float* stG  = z2 + NN;                          // 1024
  float* stT  = stG + 1024;                       // 4 x 1024
  int* counts = (int*)(stT + 4*1024);             // 64
  unsigned* mx = (unsigned*)(counts + 64);        // 64
  unsigned* mn = mx + 64;                         // 64
  int* deg  = (int*)(mn + 64);                    // NN
  int* off  = deg + NN;                           // NN
  int* cur  = off + NN;                           // NN
  int* srcs = cur + NN;                           // NE
  int* m[5];
  m[0] = srcs + NE;
  for (int k=1;k<5;k++) m[k] = m[k-1] + NN;
  unsigned short* wt[7];
  wt[0] = (unsigned short*)(m[4] + NN);
  for (int k=1;k<7;k++) wt[k] = wt[k-1] + HD*HD;
  unsigned short* w1t = wt[6] + HD*HD;            // 64*512 fp16

  const int TPB = 256;
  dim3 gN((NN+TPB-1)/TPB);
  dim3 gE((NE+TPB-1)/TPB);
  dim3 gNH((unsigned)((NH + TPB-1)/TPB));
  dim3 gNH2((unsigned)((NH/2 + TPB-1)/TPB));
  dim3 gmfma((NN+127)/128, HD/128);
  dim3 gtr(HD/32, HD/32);
  dim3 ghead((NN+127)/128);

  // setup
  hipMemsetAsync(counts, 0, 64*sizeof(int), stream);
  k_counts<<<gN, TPB, 0, stream>>>(batch, counts);
  k_invs_mask0<<<gN, TPB, 0, stream>>>(batch, counts, x, invs, m[0]);
  for (int k=1;k<5;k++){
    k_mask_copy<<<gN,TPB,0,stream>>>(m[k-1], m[k]);
    k_mask_prop<<<gE,TPB,0,stream>>>(m[k-1], m[k], src, dst);
  }
  // CSR by dst
  hipMemsetAsync(deg, 0, NN*sizeof(int), stream);
  k_deg<<<gE,TPB,0,stream>>>(dst, deg);
  k_scan<<<1,1024,0,stream>>>(deg, off, cur);
  k_scatter<<<gE,TPB,0,stream>>>(src, dst, cur, srcs);
  // weight prep (fp16 transposed)
  k_w2ht<<<gtr,256,0,stream>>>(c1_w2, wt[0], HD, HD);
  for (int i=0;i<3;i++){
    k_w2ht<<<gtr,256,0,stream>>>(cw1 + (size_t)i*HD*HD, wt[1+i], HD, HD);
    k_w2ht<<<gtr,256,0,stream>>>(cw2 + (size_t)i*HD*HD, wt[4+i], HD, HD);
  }
  k_w2ht<<<dim3(HD/32, HIDN/32),256,0,stream>>>(l1_w, w1t, HD, HIDN);

  // conv1: h1->buf1, gemm(+stats)->buf2, apply<false>->buf0 (= T0, stats stT[0])
  k_sagg_csr<<<gN,TPB,0,stream>>>(x, off, deg, srcs, eps1, h0);
  k_conv1_h1<<<gNH,TPB,0,stream>>>(h0, c1_w1, c1_b1, buf1);
  hipMemsetAsync(stG, 0, 1024*sizeof(float), stream);
  k_gemm_mfma<true><<<gmfma,256,0,stream>>>((const _Float16*)buf1, (const _Float16*)wt[0], c1_b2, (_Float16*)buf2, stG, NN);
  hipMemsetAsync(stT, 0, 1024*sizeof(float), stream);
  k_bn_apply_stats<false><<<512,256,0,stream>>>((unsigned*)buf2, c1_bng, c1_bnb, stG,
      nullptr, nullptr, nullptr, nullptr, m[1], invs, (unsigned*)buf0, stT);

  // rotation state: P holds T_prev (fp16, raw pre-BN); affinePrev = (stPrev, gPrev, bPrev)
  unsigned short *P = buf0, *Q = buf1, *R = buf2;
  const float* stPrev = stT;
  const float* gPrev = bn1_g;
  const float* bPrev = bn1_b;

  for (int i=0;i<3;i++){
    // agg applies prev affine on the fly: P -> Q
    k_agg_csr<<<NN,64,0,stream>>>((const _Float16*)P, off, deg, srcs, ceps+i,
                                  stPrev, gPrev, bPrev, (_Float16*)Q);
    k_gemm_mfma<false><<<gmfma,256,0,stream>>>((const _Float16*)Q, (const _Float16*)wt[1+i], cb1 + (size_t)i*HD, (_Float16*)R, nullptr, NN);
    hipMemsetAsync(stG, 0, 1024*sizeof(float), stream);
    k_gemm_mfma<true><<<gmfma,256,0,stream>>>((const _Float16*)R, (const _Float16*)wt[4+i], cb2 + (size_t)i*HD, (_Float16*)Q, stG, NN);
    float* stCur = stT + (i+1)*1024;
    hipMemsetAsync(stCur, 0, 1024*sizeof(float), stream);
    k_bn_apply_stats<true><<<512,256,0,stream>>>((unsigned*)Q, cbn_g + (size_t)i*HD, cbn_b + (size_t)i*HD, stG,
        (unsigned*)P, stPrev, gPrev, bPrev, m[i+2], invs, (unsigned*)R, stCur);
    // rotate: T_i is in R
    unsigned short* tmp = P; P = R; R = tmp;
    stPrev = stCur;
    gPrev = bns_g + (size_t)i*HD;
    bPrev = bns_b + (size_t)i*HD;
  }

  // materialize Xh once: Q = affinePrev(P)
  k_bn_final<<<gNH2,TPB,0,stream>>>((const unsigned*)P, gPrev, bPrev, stPrev, (unsigned*)Q);

  // head: fused lin1+lin2 + per-block LDS minmax, then normalize
  hipMemsetAsync(mx, 0x00, 64*sizeof(unsigned), stream);
  hipMemsetAsync(mn, 0xFF, 64*sizeof(unsigned), stream);
  k_head<<<ghead,256,0,stream>>>((const _Float16*)Q, (const _Float16*)w1t, l1_b, l2_w, l2_b,
                                 m[4], batch, z2, mx, mn, NN);
  k_final<<<gN,TPB,0,stream>>>(z2, batch, mx, mn, out);
}